// Round 12
// baseline (154.900 us; speedup 1.0000x reference)
//
#include <hip/hip_runtime.h>
#include <hip/hip_bf16.h>
#include <math.h>

#define Bb 2
#define NQn 256
#define NSn 1024
#define Dn 256
#define Hn 8
#define DHn 32
#define FFNn 1024
#define RPEn 512
#define SCALEf 0.17677669529663687f
#define EPSf 1e-5f

// async global->LDS, 16B per lane. LDS dest must be linear in lane order
// (wave-uniform base + lane*16); global src is per-lane (pre-swizzled).
#define GLDS16(g, l)                                                         \
  __builtin_amdgcn_global_load_lds(                                          \
      (const __attribute__((address_space(1))) void*)(const void*)(g),       \
      (__attribute__((address_space(3))) void*)(void*)(l), 16, 0, 0)

// ---------------------------------------------------------------------------
// gemmN body: 64x64 tile, 256 threads, 4x4 acc/thread, K-step 32.
// BOTH operands staged k-major (AsT/WsT [32][68]) so the inner loop is
// 2x ds_read_b128 + 16 FMA per k (VALU-bound, not LDS-bound).
// A-read: 16-lane broadcast (free). W-read: 2-way (free).
// Register prefetch of next K-chunk. Optional split-K (k00/Kchunk) and
// trsh!=0 head-major transposed store for K/V.
// ---------------------------------------------------------------------------
__device__ __forceinline__ void gemmN_body(
    float* __restrict__ C, int ldc,
    const float* __restrict__ A, const float* __restrict__ A2, int ld,
    const float* __restrict__ W, const float* __restrict__ bias,
    int k00, int Kchunk, int bm, int bnC, int bnW,
    float scale, int do_relu, int trsh,
    float (*AsT)[68], float (*WsT)[68])
{
  const int tid = threadIdx.x;
  const int tx = tid & 15, ty = tid >> 4;       // n0 = tx*4, m0 = ty*4
  const int sr = tid >> 2, sq = (tid & 3) * 8;  // staging: row, k-offset
  float4 ra0, ra1, rw0, rw1;
  {
    const float* Ap = A + (size_t)(bm + sr) * ld + k00 + sq;
    ra0 = *(const float4*)Ap;
    ra1 = *(const float4*)(Ap + 4);
    if (A2) {
      const float* Bp = A2 + (size_t)(bm + sr) * ld + k00 + sq;
      float4 t0 = *(const float4*)Bp, t1 = *(const float4*)(Bp + 4);
      ra0.x += t0.x; ra0.y += t0.y; ra0.z += t0.z; ra0.w += t0.w;
      ra1.x += t1.x; ra1.y += t1.y; ra1.z += t1.z; ra1.w += t1.w;
    }
    const float* Wp = W + (size_t)(bnW + sr) * ld + k00 + sq;
    rw0 = *(const float4*)Wp;
    rw1 = *(const float4*)(Wp + 4);
  }
  float acc[4][4] = {};
  for (int k0 = k00; k0 < k00 + Kchunk; k0 += 32) {
    AsT[sq + 0][sr] = ra0.x; AsT[sq + 1][sr] = ra0.y;
    AsT[sq + 2][sr] = ra0.z; AsT[sq + 3][sr] = ra0.w;
    AsT[sq + 4][sr] = ra1.x; AsT[sq + 5][sr] = ra1.y;
    AsT[sq + 6][sr] = ra1.z; AsT[sq + 7][sr] = ra1.w;
    WsT[sq + 0][sr] = rw0.x; WsT[sq + 1][sr] = rw0.y;
    WsT[sq + 2][sr] = rw0.z; WsT[sq + 3][sr] = rw0.w;
    WsT[sq + 4][sr] = rw1.x; WsT[sq + 5][sr] = rw1.y;
    WsT[sq + 6][sr] = rw1.z; WsT[sq + 7][sr] = rw1.w;
    __syncthreads();
    if (k0 + 32 < k00 + Kchunk) {
      const float* Ap = A + (size_t)(bm + sr) * ld + k0 + 32 + sq;
      ra0 = *(const float4*)Ap;
      ra1 = *(const float4*)(Ap + 4);
      if (A2) {
        const float* Bp = A2 + (size_t)(bm + sr) * ld + k0 + 32 + sq;
        float4 t0 = *(const float4*)Bp, t1 = *(const float4*)(Bp + 4);
        ra0.x += t0.x; ra0.y += t0.y; ra0.z += t0.z; ra0.w += t0.w;
        ra1.x += t1.x; ra1.y += t1.y; ra1.z += t1.z; ra1.w += t1.w;
      }
      const float* Wp = W + (size_t)(bnW + sr) * ld + k0 + 32 + sq;
      rw0 = *(const float4*)Wp;
      rw1 = *(const float4*)(Wp + 4);
    }
#pragma unroll
    for (int k = 0; k < 32; ++k) {
      float4 a = *(const float4*)&AsT[k][ty * 4];
      float4 w = *(const float4*)&WsT[k][tx * 4];
      acc[0][0] += a.x * w.x; acc[0][1] += a.x * w.y;
      acc[0][2] += a.x * w.z; acc[0][3] += a.x * w.w;
      acc[1][0] += a.y * w.x; acc[1][1] += a.y * w.y;
      acc[1][2] += a.y * w.z; acc[1][3] += a.y * w.w;
      acc[2][0] += a.z * w.x; acc[2][1] += a.z * w.y;
      acc[2][2] += a.z * w.z; acc[2][3] += a.z * w.w;
      acc[3][0] += a.w * w.x; acc[3][1] += a.w * w.y;
      acc[3][2] += a.w * w.z; acc[3][3] += a.w * w.w;
    }
    __syncthreads();
  }
  const int nC = bnC + tx * 4;
  const int nW = bnW + tx * 4;
#pragma unroll
  for (int i = 0; i < 4; ++i) {
    const int m = bm + ty * 4 + i;
    float4 v;
    v.x = acc[i][0]; v.y = acc[i][1]; v.z = acc[i][2]; v.w = acc[i][3];
    if (bias) {
      v.x += bias[nW + 0]; v.y += bias[nW + 1];
      v.z += bias[nW + 2]; v.w += bias[nW + 3];
    }
    v.x *= scale; v.y *= scale; v.z *= scale; v.w *= scale;
    if (do_relu) {
      v.x = fmaxf(v.x, 0.f); v.y = fmaxf(v.y, 0.f);
      v.z = fmaxf(v.z, 0.f); v.w = fmaxf(v.w, 0.f);
    }
    if (trsh == 0) {
      *(float4*)&C[(size_t)m * ldc + nC] = v;
    } else {
      const int bb = m >> trsh, kseq = m & ((1 << trsh) - 1);
      const int hh = nC >> 5, d0 = nC & 31;
      *(float4*)&C[((((size_t)(bb * Hn + hh)) << trsh) + kseq) * 32 + d0] = v;
    }
  }
}

// ---------------------------------------------------------------------------
// prep: fused build_cpb (1 tile, 256-thr variant) + self QKV GEMM (96 tiles;
// K/V head-major transposed) + cross KV GEMM (256 tiles). 256 threads.
// ---------------------------------------------------------------------------
__global__ __launch_bounds__(256) void prep_kernel(
    float* __restrict__ qSb, float* __restrict__ kSb, float* __restrict__ vSb,
    float* __restrict__ kCb, float* __restrict__ vCb,
    const float* __restrict__ tgt, const float* __restrict__ qpos,
    const float* __restrict__ src, const float* __restrict__ spe,
    const float* __restrict__ ipw, const float* __restrict__ ipb,
    const float* __restrict__ kw, const float* __restrict__ kb,
    const float* __restrict__ vw, const float* __restrict__ vb,
    const float* __restrict__ w1p, const float* __restrict__ b1p,
    const float* __restrict__ w2p,
    float* __restrict__ tout, float* __restrict__ Stab, float* __restrict__ Btab)
{
  __shared__ float smem[4352];  // AsT 32*68=2176 + WsT 2176 (cpb reuses)
  const int bx = blockIdx.x;
  const int tid = threadIdx.x;
  if (bx < 96) {
    float (*AsT)[68] = (float(*)[68])smem;
    float (*WsT)[68] = (float(*)[68])(smem + 2176);
    int my = bx & 7, nx = bx >> 3;
    int sec = nx >> 2;
    float* C = sec == 0 ? qSb : (sec == 1 ? kSb : vSb);
    gemmN_body(C, Dn, tgt, sec < 2 ? qpos : nullptr, Dn, ipw, ipb,
               0, Dn, my * 64, (nx & 3) * 64, nx * 64,
               sec == 0 ? SCALEf : 1.f, 0, sec == 0 ? 0 : 8, AsT, WsT);
    return;
  }
  if (bx < 96 + 256) {
    float (*AsT)[68] = (float(*)[68])smem;
    float (*WsT)[68] = (float(*)[68])(smem + 2176);
    int idx = bx - 96;
    int my = idx & 31, nx = idx >> 5;
    int sec = nx >> 2;
    gemmN_body(sec ? vCb : kCb, Dn, src, sec ? nullptr : spe, Dn,
               sec ? vw : kw, sec ? vb : kb,
               0, Dn, my * 64, (nx & 3) * 64, (nx & 3) * 64, 1.f, 0, 10,
               AsT, WsT);
    return;
  }
  // ---- cpb piecewise-linear table build (256-thread adaptation of the
  //      verified 512-thread version: 2 elements/thread, 2 heads/wave) ----
  float* key = smem;
  int* pidx = (int*)(smem + 512);
  float* w1s = smem + 1024;
  float* b1s = smem + 1536;
  for (int e = 0; e < 2; ++e) {
    int i = tid + e * 256;
    float w = w1p[i], bb = b1p[i];
    key[i] = (w != 0.f) ? (-bb / w) : 3.0e38f;
    pidx[i] = i;
  }
  __syncthreads();
  for (int k = 2; k <= RPEn; k <<= 1) {
    for (int j = k >> 1; j > 0; j >>= 1) {
      for (int e = 0; e < 2; ++e) {
        int i = tid + e * 256;
        int ixj = i ^ j;
        if (ixj > i) {
          float a = key[i], c = key[ixj];
          bool asc = ((i & k) == 0);
          if (asc ? (a > c) : (a < c)) {
            key[i] = c; key[ixj] = a;
            int tmp = pidx[i]; pidx[i] = pidx[ixj]; pidx[ixj] = tmp;
          }
        }
      }
      __syncthreads();
    }
  }
  for (int e = 0; e < 2; ++e) {
    int i = tid + e * 256;
    w1s[i] = w1p[pidx[i]];
    b1s[i] = b1p[pidx[i]];
    tout[i] = key[i];
  }
  __syncthreads();
  const int lane = tid & 63;
  for (int hh = 0; hh < 2; ++hh) {
    const int h = (tid >> 6) * 2 + hh;
    const int j0 = lane * 8;
    float sp[8], bp[8], sn[8], bn[8];
    float csp = 0.f, cbp = 0.f, csn = 0.f, cbn = 0.f, ccc = 0.f;
#pragma unroll
    for (int e = 0; e < 8; ++e) {
      int j = j0 + e;
      float w = w1s[j], b = b1s[j];
      float c = w2p[h * RPEn + pidx[j]];
      sp[e] = csp; bp[e] = cbp; sn[e] = csn; bn[e] = cbn;
      if (w > 0.f)      { csp += w * c; cbp += b * c; }
      else if (w < 0.f) { csn += w * c; cbn += b * c; }
      else              { ccc += fmaxf(b, 0.f) * c; }
    }
    float isp = csp, ibp = cbp, isn = csn, ibn = cbn, icc = ccc;
#pragma unroll
    for (int d = 1; d < 64; d <<= 1) {
      float t0 = __shfl_up(isp, d);
      float t1 = __shfl_up(ibp, d);
      float t2 = __shfl_up(isn, d);
      float t3 = __shfl_up(ibn, d);
      if (lane >= d) { isp += t0; ibp += t1; isn += t2; ibn += t3; }
      icc += __shfl_xor(icc, d);
    }
    const float tsn = __shfl(isn, 63);
    const float tbn = __shfl(ibn, 63);
    const float esp = isp - csp, ebp = ibp - cbp;
    const float esn = isn - csn, ebn = ibn - cbn;
#pragma unroll
    for (int e = 0; e < 8; ++e) {
      int j = j0 + e;
      Stab[j * Hn + h] = (esp + sp[e]) + (tsn - (esn + sn[e]));
      Btab[j * Hn + h] = (ebp + bp[e]) + (tbn - (ebn + bn[e])) + icc;
    }
    if (lane == 63) {
      Stab[RPEn * Hn + h] = isp;
      Btab[RPEn * Hn + h] = ibp + icc;
    }
  }
}

// ---------------------------------------------------------------------------
// bias_kernel: materialize bias[b,h,q,k] = Sh[lo]*m + Bh[lo] - 100*pad.
// Binary search depends only on (b,q,k) -> done ONCE, applied to 8 heads.
// ---------------------------------------------------------------------------
__global__ __launch_bounds__(256) void bias_kernel(
    float* __restrict__ biasb, const float* __restrict__ rel,
    const float* __restrict__ pad, const float* __restrict__ tsg,
    const float* __restrict__ Stabg, const float* __restrict__ Btabg)
{
  __shared__ float ts[RPEn];
  __shared__ float Sh[(RPEn + 1) * Hn];
  __shared__ float Bh[(RPEn + 1) * Hn];
  const int tid = threadIdx.x;
  const int b = blockIdx.x >> 8, q = blockIdx.x & 255;
  ts[tid] = tsg[tid];
  ts[tid + 256] = tsg[tid + 256];
  for (int i = tid; i < (RPEn + 1) * Hn; i += 256) {
    Sh[i] = Stabg[i];
    Bh[i] = Btabg[i];
  }
  __syncthreads();
#pragma unroll
  for (int j = 0; j < 4; ++j) {
    const int k = tid + j * 256;
    const float m = rel[((size_t)b * NQn + q) * NSn + k];
    const float padv = -100.f * pad[b * NSn + k];
    int lo = 0, hi = RPEn;
#pragma unroll
    for (int it = 0; it < 9; ++it) {
      int mid = (lo + hi) >> 1;
      if (ts[mid] < m) lo = mid + 1; else hi = mid;
    }
#pragma unroll
    for (int h = 0; h < Hn; ++h) {
      biasb[(((size_t)(b * Hn + h)) * NQn + q) * NSn + k] =
          Sh[lo * Hn + h] * m + Bh[lo * Hn + h] + padv;
    }
  }
}

// ---------------------------------------------------------------------------
// Flash attention, R=2 rows/thread, HEAD-MAJOR K/V (verified round 11).
// Rotation swizzle in ADDRESS arithmetic only; registers statically indexed.
// ---------------------------------------------------------------------------
__global__ __launch_bounds__(256, 2) void flash_kernel(
    float* __restrict__ O, const float* __restrict__ Q,
    const float* __restrict__ kT, const float* __restrict__ vT,
    const float* __restrict__ biasb, int NK)
{
  __shared__ float4 Ks[2][1024];
  __shared__ float4 Vs[2][1024];
  __shared__ float4 Qs[64];
  const int bh = blockIdx.y, b = bh >> 3, h = bh & 7;
  const int q0 = blockIdx.x * 8;
  const int tid = threadIdx.x;
  const int w = tid >> 6, kc = tid & 63;
  const float4* Ktp = (const float4*)kT + (size_t)bh * NK * 8;
  const float4* Vtp = (const float4*)vT + (size_t)bh * NK * 8;
  if (tid < 64)
    Qs[tid] = ((const float4*)Q)[(size_t)(b * NQn + q0 + (tid >> 3)) * 64 +
                                 h * 8 + (tid & 7)];

  const float* brow0 =
      biasb ? biasb + ((size_t)bh * NQn + q0 + 2 * w) * NK : nullptr;
  const float* brow1 = biasb ? brow0 + NK : nullptr;

  auto stage = [&](int buf, int kb0) {
#pragma unroll
    for (int u = 0; u < 4; ++u) {
      const int s = tid + u * 256;   // linear LDS slot (lane order)
      const int k = s >> 3, e = s & 7;
      const int g = (kb0 + k) * 8 + ((e - k) & 7);
      GLDS16(Ktp + g, &Ks[buf][s]);
      GLDS16(Vtp + g, &Vs[buf][s]);
    }
  };

  stage(0, 0);
  float cb[2][2];
  if (biasb) {
    cb[0][0] = brow0[kc]; cb[0][1] = brow0[kc + 64];
    cb[1][0] = brow1[kc]; cb[1][1] = brow1[kc + 64];
  }
  __syncthreads();

  float4 q[2][8];
#pragma unroll
  for (int dd = 0; dd < 8; ++dd) {
    q[0][dd] = Qs[(2 * w) * 8 + dd];
    q[1][dd] = Qs[(2 * w + 1) * 8 + dd];
  }
  float4 o[2][8] = {};
  float m_run[2] = {-3.0e38f, -3.0e38f};
  float l_run[2] = {0.f, 0.f};
  const int nchunk = NK >> 7;

  for (int c = 0; c < nchunk; ++c) {
    const int cur = c & 1;
    float nb[2][2];
    if (c + 1 < nchunk) {
      stage(cur ^ 1, (c + 1) * 128);
      if (biasb) {
        nb[0][0] = brow0[(c + 1) * 128 + kc];
        nb[0][1] = brow0[(c + 1) * 128 + kc + 64];
        nb[1][0] = brow1[(c + 1) * 128 + kc];
        nb[1][1] = brow1[(c + 1) * 128 + kc + 64];
      }
    }
    float s[2][2];
#pragma unroll
    for (int j = 0; j < 2; ++j) {
      const int kbase = (kc + j * 64) * 8;
      float4 a0 = {0.f, 0.f, 0.f, 0.f};
      float4 a1 = {0.f, 0.f, 0.f, 0.f};
#pragma unroll
      for (int dd = 0; dd < 8; ++dd) {
        float4 kk = Ks[cur][kbase + ((dd + kc) & 7)];
        a0.x += q[0][dd].x * kk.x; a0.y += q[0][dd].y * kk.y;
        a0.z += q[0][dd].z * kk.z; a0.w += q[0][dd].w * kk.w;
        a1.x += q[1][dd].x * kk.x; a1.y += q[1][dd].y * kk.y;
        a1.z += q[1][dd].z * kk.z; a1.w += q[1][dd].w * kk.w;
      }
      s[0][j] = (a0.x + a0.y) + (a0.z + a0.w);
      s[1][j] = (a1.x + a1.y) + (a1.z + a1.w);
      if (biasb) { s[0][j] += cb[0][j]; s[1][j] += cb[1][j]; }
    }
    float f[2];
#pragma unroll
    for (int r = 0; r < 2; ++r) {
      float cmax = fmaxf(s[r][0], s[r][1]);
#pragma unroll
      for (int off = 1; off < 64; off <<= 1)
        cmax = fmaxf(cmax, __shfl_xor(cmax, off));
      const float m_new = fmaxf(m_run[r], cmax);
      f[r] = __expf(m_run[r] - m_new);
      s[r][0] = __expf(s[r][0] - m_new);
      s[r][1] = __expf(s[r][1] - m_new);
      float ls = s[r][0] + s[r][1];
#pragma unroll
      for (int off = 1; off < 64; off <<= 1) ls += __shfl_xor(ls, off);
      l_run[r] = l_run[r] * f[r] + ls;
      m_run[r] = m_new;
    }
#pragma unroll
    for (int dd = 0; dd < 8; ++dd) {
      o[0][dd].x *= f[0]; o[0][dd].y *= f[0]; o[0][dd].z *= f[0]; o[0][dd].w *= f[0];
      o[1][dd].x *= f[1]; o[1][dd].y *= f[1]; o[1][dd].z *= f[1]; o[1][dd].w *= f[1];
    }
#pragma unroll
    for (int j = 0; j < 2; ++j) {
      const int kbase = (kc + j * 64) * 8;
      const float p0 = s[0][j], p1 = s[1][j];
#pragma unroll
      for (int dd = 0; dd < 8; ++dd) {
        float4 vv = Vs[cur][kbase + ((dd + kc) & 7)];
        o[0][dd].x += p0 * vv.x; o[0][dd].y += p0 * vv.y;
        o[0][dd].z += p0 * vv.z; o[0][dd].w += p0 * vv.w;
        o[1][dd].x += p1 * vv.x; o[1][dd].y += p1 * vv.y;
        o[1][dd].z += p1 * vv.z; o[1][dd].w += p1 * vv.w;
      }
    }
    if (biasb && c + 1 < nchunk) {
      cb[0][0] = nb[0][0]; cb[0][1] = nb[0][1];
      cb[1][0] = nb[1][0]; cb[1][1] = nb[1][1];
    }
    __syncthreads();
  }
#pragma unroll
  for (int off = 1; off < 64; off <<= 1) {
#pragma unroll
    for (int dd = 0; dd < 8; ++dd) {
      o[0][dd].x += __shfl_xor(o[0][dd].x, off);
      o[0][dd].y += __shfl_xor(o[0][dd].y, off);
      o[0][dd].z += __shfl_xor(o[0][dd].z, off);
      o[0][dd].w += __shfl_xor(o[0][dd].w, off);
      o[1][dd].x += __shfl_xor(o[1][dd].x, off);
      o[1][dd].y += __shfl_xor(o[1][dd].y, off);
      o[1][dd].z += __shfl_xor(o[1][dd].z, off);
      o[1][dd].w += __shfl_xor(o[1][dd].w, off);
    }
  }
  if (kc == 0) {
    const float inv = 1.f / l_run[0];
#pragma unroll
    for (int dd = 0; dd < 8; ++dd) {
      float4 v = o[0][dd];
      v.x *= inv; v.y *= inv; v.z *= inv; v.w *= inv;
      ((float4*)O)[(size_t)(b * NQn + q0 + 2 * w) * 64 + h * 8 + dd] = v;
    }
  } else if (kc == 1) {
    const float inv = 1.f / l_run[1];
#pragma unroll
    for (int dd = 0; dd < 8; ++dd) {
      float4 v = o[1][dd];
      v.x *= inv; v.y *= inv; v.z *= inv; v.w *= inv;
      ((float4*)O)[(size_t)(b * NQn + q0 + 2 * w + 1) * 64 + h * 8 + dd] = v;
    }
  }
}

// ---------------------------------------------------------------------------
// gemmN standalone: grid (N/64, M/64, nsplit), 256 threads.
// nsplit>1: writes partials at kz*M*ldc with bias deferred to the reducer.
// ---------------------------------------------------------------------------
__global__ __launch_bounds__(256) void gemmN_kernel(
    float* __restrict__ C, const float* __restrict__ A,
    const float* __restrict__ A2, const float* __restrict__ W,
    const float* __restrict__ bias, int ld, int ldc, int Ktot, int nsplit,
    float scale, int do_relu)
{
  __shared__ float smem[4352];
  float (*AsT)[68] = (float(*)[68])smem;
  float (*WsT)[68] = (float(*)[68])(smem + 2176);
  const int kz = blockIdx.z;
  const int Kchunk = Ktot / nsplit;
  const int M = gridDim.y * 64;
  float* Cp = C + (size_t)kz * M * ldc;
  gemmN_body(Cp, ldc, A, A2, ld, W, nsplit == 1 ? bias : nullptr,
             kz * Kchunk, Kchunk, blockIdx.y * 64, blockIdx.x * 64,
             blockIdx.x * 64, scale, do_relu, 0, AsT, WsT);
}

// ---------------------------------------------------------------------------
// out = LayerNorm(x1 + x2) * g + b.  grid: rows, block = 256 = D.
// ---------------------------------------------------------------------------
__global__ __launch_bounds__(256) void add_ln_kernel(
    float* __restrict__ out, const float* __restrict__ x1, const float* __restrict__ x2,
    const float* __restrict__ g, const float* __restrict__ bt)
{
  const int row = blockIdx.x;
  const int t = threadIdx.x;
  const float v = x1[(size_t)row * Dn + t] + x2[(size_t)row * Dn + t];
  float s = v, s2 = v * v;
#pragma unroll
  for (int off = 32; off > 0; off >>= 1) {
    s += __shfl_down(s, off);
    s2 += __shfl_down(s2, off);
  }
  __shared__ float rs[4], rs2[4], fin[2];
  const int lane = t & 63, wid = t >> 6;
  if (lane == 0) { rs[wid] = s; rs2[wid] = s2; }
  __syncthreads();
  if (t == 0) {
    float a = rs[0] + rs[1] + rs[2] + rs[3];
    float a2 = rs2[0] + rs2[1] + rs2[2] + rs2[3];
    float mean = a * (1.f / Dn);
    float var = a2 * (1.f / Dn) - mean * mean;
    fin[0] = mean;
    fin[1] = rsqrtf(var + EPSf);
  }
  __syncthreads();
  out[(size_t)row * Dn + t] = (v - fin[0]) * fin[1] * g[t] + bt[t];
}

// ---------------------------------------------------------------------------
// out = LayerNorm(resid + sum_{kz<4} part[kz] + bias) * g + b (split-K reduce)
// ---------------------------------------------------------------------------
__global__ __launch_bounds__(256) void reduce_ln_kernel(
    float* __restrict__ out, const float* __restrict__ part,
    const float* __restrict__ bias, const float* __restrict__ resid,
    const float* __restrict__ g, const float* __restrict__ bt)
{
  const int row = blockIdx.x;
  const int t = threadIdx.x;
  const size_t idx = (size_t)row * Dn + t;
  const size_t STR = (size_t)Bb * NQn * Dn;
  float v = part[idx] + part[idx + STR] + part[idx + 2 * STR] + part[idx + 3 * STR]
          + bias[t] + resid[idx];
  float s = v, s2 = v * v;
#pragma unroll
  for (int off = 32; off > 0; off >>= 1) {
    s += __shfl_down(s, off);
    s2 += __shfl_down(s2, off);
  }
  __shared__ float rs[4], rs2[4], fin[2];
  const int lane = t & 63, wid = t >> 6;
  if (lane == 0) { rs[wid] = s; rs2[wid] = s2; }
  __syncthreads();
  if (t == 0) {
    float a = rs[0] + rs[1] + rs[2] + rs[3];
    float a2 = rs2[0] + rs2[1] + rs2[2] + rs2[3];
    float mean = a * (1.f / Dn);
    float var = a2 * (1.f / Dn) - mean * mean;
    fin[0] = mean;
    fin[1] = rsqrtf(var + EPSf);
  }
  __syncthreads();
  out[idx] = (v - fin[0]) * fin[1] * g[t] + bt[t];
}

extern "C" void kernel_launch(void* const* d_in, const int* in_sizes, int n_in,
                              void* d_out, int out_size, void* d_ws, size_t ws_size,
                              hipStream_t stream)
{
  const float* tgt   = (const float*)d_in[0];
  const float* qpos  = (const float*)d_in[1];
  const float* src   = (const float*)d_in[2];
  const float* spe   = (const float*)d_in[3];
  const float* pad   = (const float*)d_in[4];
  const float* rel   = (const float*)d_in[5];
  const float* qw    = (const float*)d_in[6];
  const float* qb    = (const float*)d_in[7];
  const float* kw    = (const float*)d_in[8];
  const float* kb    = (const float*)d_in[9];
  const float* vw    = (const float*)d_in[10];
  const float* vb    = (const float*)d_in[11];
  const float* projw = (const float*)d_in[12];
  const float* projb = (const float*)d_in[13];
  const float* cpbw1 = (const float*)d_in[14];
  const float* cpbb1 = (const float*)d_in[15];
  const float* cpbw2 = (const float*)d_in[16];
  const float* ipw   = (const float*)d_in[17];
  const float* ipb   = (const float*)d_in[18];
  const float* outw  = (const float*)d_in[19];
  const float* outb  = (const float*)d_in[20];
  const float* ln1g  = (const float*)d_in[21];
  const float* ln1b  = (const float*)d_in[22];
  const float* ln2g  = (const float*)d_in[23];
  const float* ln2b  = (const float*)d_in[24];
  const float* ln3g  = (const float*)d_in[25];
  const float* ln3b  = (const float*)d_in[26];
  const float* ff1w  = (const float*)d_in[27];
  const float* ff1b  = (const float*)d_in[28];
  const float* ff2w  = (const float*)d_in[29];
  const float* ff2b  = (const float*)d_in[30];
  float* out = (float*)d_out;
  float* ws = (float*)d_ws;

  constexpr size_t SZ_Q   = (size_t)Bb * NQn * Dn;   // 131072
  constexpr size_t SZ_S   = (size_t)Bb * NSn * Dn;   // 524288
  constexpr size_t SZ_FFH = (size_t)Bb * NQn * FFNn; // 524288

  float* qSb  = ws;
  float* kSb  = qSb + SZ_Q;   // head-major kT (self)
  float* vSb  = kSb + SZ_Q;   // head-major vT (self)
  float* oSb  = vSb + SZ_Q;
  float* soP  = oSb + SZ_Q;
  float* tgt2 = soP + SZ_Q;
  float* qCb  = tgt2 + SZ_Q;
  float* kCb  = qCb + SZ_Q;   // head-major kT (cross)
  float* vCb  = kCb + SZ_S;   // head-major vT (cross)
  float* oCb  = vCb + SZ_S;
  float* coP  = oCb + SZ_Q;
  float* tgt3 = coP + SZ_Q;
  float* ffh  = tgt3 + SZ_Q;
  float* part = ffh + SZ_FFH;           // 4 * SZ_Q
  float* tsb  = part + 4 * SZ_Q;
  float* Stab = tsb + RPEn;
  float* Btab = Stab + (RPEn + 1) * Hn;
  float* biasb = Btab + (RPEn + 1) * Hn;

  const int MQ = Bb * NQn;  // 512

  // 1. prep: cpb tables + self QKV + cross KV (K/V transposed head-major)
  prep_kernel<<<dim3(96 + 256 + 1), dim3(256), 0, stream>>>(
      qSb, kSb, vSb, kCb, vCb, tgt, qpos, src, spe, ipw, ipb,
      kw, kb, vw, vb, cpbw1, cpbb1, cpbw2, tsb, Stab, Btab);

  // 2. materialize cross-attn bias (search once per (b,q,k), 8 heads)
  bias_kernel<<<dim3(Bb * NQn), dim3(256), 0, stream>>>(
      biasb, rel, pad, tsb, Stab, Btab);

  // 3. self attention (R=2 flash, coalesced head-major staging)
  flash_kernel<<<dim3(NQn / 8, Bb * Hn), dim3(256), 0, stream>>>(
      oSb, qSb, kSb, vSb, nullptr, NQn);

  // 4. self out-proj
  gemmN_kernel<<<dim3(Dn / 64, MQ / 64, 1), dim3(256), 0, stream>>>(
      soP, oSb, nullptr, outw, outb, Dn, Dn, Dn, 1, 1.f, 0);

  // 5. tgt2 = LN2(tgt + soP)
  add_ln_kernel<<<dim3(MQ), dim3(256), 0, stream>>>(tgt2, tgt, soP, ln2g, ln2b);

  // 6. cross q
  gemmN_kernel<<<dim3(Dn / 64, MQ / 64, 1), dim3(256), 0, stream>>>(
      qCb, tgt2, qpos, qw, qb, Dn, Dn, Dn, 1, SCALEf, 0);

  // 7. cross attention (R=2 flash + staged bias)
  flash_kernel<<<dim3(NQn / 8, Bb * Hn), dim3(256), 0, stream>>>(
      oCb, qCb, kCb, vCb, biasb, NSn);

  // 8. cross out-proj
  gemmN_kernel<<<dim3(Dn / 64, MQ / 64, 1), dim3(256), 0, stream>>>(
      coP, oCb, nullptr, projw, projb, Dn, Dn, Dn, 1, 1.f, 0);

  // 9. tgt3 = LN1(tgt2 + coP)
  add_ln_kernel<<<dim3(MQ), dim3(256), 0, stream>>>(tgt3, tgt2, coP, ln1g, ln1b);

  // 10. FFN1 (relu)
  gemmN_kernel<<<dim3(FFNn / 64, MQ / 64, 1), dim3(256), 0, stream>>>(
      ffh, tgt3, nullptr, ff1w, ff1b, Dn, FFNn, Dn, 1, 1.f, 1);

  // 11. FFN2 split-K x4 -> partials
  gemmN_kernel<<<dim3(Dn / 64, MQ / 64, 4), dim3(256), 0, stream>>>(
      part, ffh, nullptr, ff2w, nullptr, FFNn, Dn, FFNn, 4, 1.f, 0);

  // 12. out = LN3(tgt3 + sum(part) + ff2b)
  reduce_ln_kernel<<<dim3(MQ), dim3(256), 0, stream>>>(
      out, part, ff2b, tgt3, ln3g, ln3b);
}

// Round 13
// 135.280 us; speedup vs baseline: 1.1450x; 1.1450x over previous
//
#include <hip/hip_runtime.h>
#include <hip/hip_bf16.h>
#include <hip/hip_fp16.h>
#include <math.h>

#define Bb 2
#define NQn 256
#define NSn 1024
#define Dn 256
#define Hn 8
#define DHn 32
#define FFNn 1024
#define RPEn 512
#define SCALEf 0.17677669529663687f
#define EPSf 1e-5f

// async global->LDS, 16B per lane. LDS dest must be linear in lane order
// (wave-uniform base + lane*16); global src is per-lane (pre-swizzled).
#define GLDS16(g, l)                                                         \
  __builtin_amdgcn_global_load_lds(                                          \
      (const __attribute__((address_space(1))) void*)(const void*)(g),       \
      (__attribute__((address_space(3))) void*)(void*)(l), 16, 0, 0)

// ---------------------------------------------------------------------------
// gemm64 body: 64x64 tile, 512 threads, K-step 32, float4 loads, reg prefetch.
// trsh != 0: write C transposed head-major kT[((b*H+h)<<trsh)+kseq][32].
// ---------------------------------------------------------------------------
__device__ __forceinline__ void gemm64_body(
    float* __restrict__ C, int ldc,
    const float* __restrict__ A, const float* __restrict__ A2, int ld,
    const float* __restrict__ W, const float* __restrict__ bias,
    int K, int bm, int bnC, int bnW, float scale, int do_relu, int trsh,
    float (*As)[33], float (*WsT)[68])
{
  const int tid = threadIdx.x;
  const int tx = tid & 15, ty = tid >> 4;       // ty 0..31
  const int lr = tid >> 3, lc = (tid & 7) * 4;  // staging coords
  float4 ra, rw;
  {
    ra = *(const float4*)(A + (size_t)(bm + lr) * ld + lc);
    if (A2) {
      float4 t = *(const float4*)(A2 + (size_t)(bm + lr) * ld + lc);
      ra.x += t.x; ra.y += t.y; ra.z += t.z; ra.w += t.w;
    }
    rw = *(const float4*)(W + (size_t)(bnW + lr) * ld + lc);
  }
  float acc[2][4] = {};
  for (int k0 = 0; k0 < K; k0 += 32) {
    As[lr][lc] = ra.x; As[lr][lc + 1] = ra.y;
    As[lr][lc + 2] = ra.z; As[lr][lc + 3] = ra.w;
    WsT[lc][lr] = rw.x; WsT[lc + 1][lr] = rw.y;
    WsT[lc + 2][lr] = rw.z; WsT[lc + 3][lr] = rw.w;
    __syncthreads();
    if (k0 + 32 < K) {
      ra = *(const float4*)(A + (size_t)(bm + lr) * ld + k0 + 32 + lc);
      if (A2) {
        float4 t = *(const float4*)(A2 + (size_t)(bm + lr) * ld + k0 + 32 + lc);
        ra.x += t.x; ra.y += t.y; ra.z += t.z; ra.w += t.w;
      }
      rw = *(const float4*)(W + (size_t)(bnW + lr) * ld + k0 + 32 + lc);
    }
#pragma unroll
    for (int k = 0; k < 32; ++k) {
      float a0 = As[ty][k], a1 = As[ty + 32][k];
      float4 w = *(const float4*)&WsT[k][tx * 4];
      acc[0][0] += a0 * w.x; acc[0][1] += a0 * w.y;
      acc[0][2] += a0 * w.z; acc[0][3] += a0 * w.w;
      acc[1][0] += a1 * w.x; acc[1][1] += a1 * w.y;
      acc[1][2] += a1 * w.z; acc[1][3] += a1 * w.w;
    }
    __syncthreads();
  }
#pragma unroll
  for (int i = 0; i < 2; ++i) {
    int m = bm + ty + i * 32;
#pragma unroll
    for (int j = 0; j < 4; ++j) {
      float v = acc[i][j];
      if (bias) v += bias[bnW + tx * 4 + j];
      v *= scale;
      if (do_relu) v = fmaxf(v, 0.f);
      if (trsh == 0) {
        C[(size_t)m * ldc + bnC + tx * 4 + j] = v;
      } else {
        const int nC = bnC + tx * 4 + j;
        const int bb = m >> trsh, kseq = m & ((1 << trsh) - 1);
        const int hh = nC >> 5, d = nC & 31;
        C[((((size_t)(bb * Hn + hh)) << trsh) + kseq) * 32 + d] = v;
      }
    }
  }
}

// ---------------------------------------------------------------------------
// prep: fused build_cpb (1 block) + self QKV GEMM (96 blocks; K/V written
// head-major transposed) + cross KV GEMM (256 blocks; transposed). 512 thr.
// ---------------------------------------------------------------------------
__global__ __launch_bounds__(512) void prep_kernel(
    float* __restrict__ qSb, float* __restrict__ kSb, float* __restrict__ vSb,
    float* __restrict__ kCb, float* __restrict__ vCb,
    const float* __restrict__ tgt, const float* __restrict__ qpos,
    const float* __restrict__ src, const float* __restrict__ spe,
    const float* __restrict__ ipw, const float* __restrict__ ipb,
    const float* __restrict__ kw, const float* __restrict__ kb,
    const float* __restrict__ vw, const float* __restrict__ vb,
    const float* __restrict__ w1p, const float* __restrict__ b1p,
    const float* __restrict__ w2p,
    float* __restrict__ tout, float* __restrict__ Stab, float* __restrict__ Btab)
{
  __shared__ float smem[4288];  // As 64*33=2112 + WsT 32*68=2176
  const int bx = blockIdx.x;
  const int tid = threadIdx.x;
  if (bx < 96) {
    float (*As)[33] = (float(*)[33])smem;
    float (*WsT)[68] = (float(*)[68])(smem + 2112);
    int my = bx & 7, nx = bx >> 3;
    int sec = nx >> 2;
    float* C = sec == 0 ? qSb : (sec == 1 ? kSb : vSb);
    gemm64_body(C, Dn, tgt, sec < 2 ? qpos : nullptr, Dn, ipw, ipb,
                Dn, my * 64, (nx & 3) * 64, nx * 64,
                sec == 0 ? SCALEf : 1.f, 0, sec == 0 ? 0 : 8, As, WsT);
    return;
  }
  if (bx < 96 + 256) {
    float (*As)[33] = (float(*)[33])smem;
    float (*WsT)[68] = (float(*)[68])(smem + 2112);
    int idx = bx - 96;
    int my = idx & 31, nx = idx >> 5;
    int sec = nx >> 2;
    gemm64_body(sec ? vCb : kCb, Dn, src, sec ? nullptr : spe, Dn,
                sec ? vw : kw, sec ? vb : kb,
                Dn, my * 64, (nx & 3) * 64, (nx & 3) * 64, 1.f, 0, 10, As, WsT);
    return;
  }
  // ---- cpb piecewise-linear table build (verified rounds 1-11) ----
  float* key = smem;
  int* pidx = (int*)(smem + 512);
  float* w1s = smem + 1024;
  float* b1s = smem + 1536;
  {
    float w = w1p[tid], bb = b1p[tid];
    key[tid] = (w != 0.f) ? (-bb / w) : 3.0e38f;
    pidx[tid] = tid;
  }
  __syncthreads();
  for (int k = 2; k <= RPEn; k <<= 1) {
    for (int j = k >> 1; j > 0; j >>= 1) {
      int ixj = tid ^ j;
      if (ixj > tid) {
        float a = key[tid], c = key[ixj];
        bool asc = ((tid & k) == 0);
        bool sw = asc ? (a > c) : (a < c);
        if (sw) {
          key[tid] = c; key[ixj] = a;
          int tmp = pidx[tid]; pidx[tid] = pidx[ixj]; pidx[ixj] = tmp;
        }
      }
      __syncthreads();
    }
  }
  w1s[tid] = w1p[pidx[tid]];
  b1s[tid] = b1p[pidx[tid]];
  tout[tid] = key[tid];
  __syncthreads();
  const int lane = tid & 63;
  const int h = tid >> 6;
  const int j0 = lane * 8;
  float sp[8], bp[8], sn[8], bn[8];
  float csp = 0.f, cbp = 0.f, csn = 0.f, cbn = 0.f, ccc = 0.f;
#pragma unroll
  for (int e = 0; e < 8; ++e) {
    int j = j0 + e;
    float w = w1s[j], b = b1s[j];
    float c = w2p[h * RPEn + pidx[j]];
    sp[e] = csp; bp[e] = cbp; sn[e] = csn; bn[e] = cbn;
    if (w > 0.f)      { csp += w * c; cbp += b * c; }
    else if (w < 0.f) { csn += w * c; cbn += b * c; }
    else              { ccc += fmaxf(b, 0.f) * c; }
  }
  float isp = csp, ibp = cbp, isn = csn, ibn = cbn, icc = ccc;
#pragma unroll
  for (int d = 1; d < 64; d <<= 1) {
    float t0 = __shfl_up(isp, d);
    float t1 = __shfl_up(ibp, d);
    float t2 = __shfl_up(isn, d);
    float t3 = __shfl_up(ibn, d);
    if (lane >= d) { isp += t0; ibp += t1; isn += t2; ibn += t3; }
    icc += __shfl_xor(icc, d);
  }
  const float tsn = __shfl(isn, 63);
  const float tbn = __shfl(ibn, 63);
  const float esp = isp - csp, ebp = ibp - cbp;
  const float esn = isn - csn, ebn = ibn - cbn;
#pragma unroll
  for (int e = 0; e < 8; ++e) {
    int j = j0 + e;
    Stab[j * Hn + h] = (esp + sp[e]) + (tsn - (esn + sn[e]));
    Btab[j * Hn + h] = (ebp + bp[e]) + (tbn - (ebn + bn[e])) + icc;
  }
  if (lane == 63) {
    Stab[RPEn * Hn + h] = isp;
    Btab[RPEn * Hn + h] = ibp + icc;
  }
}

// ---------------------------------------------------------------------------
// bias_kernel: materialize bias[b,h,q,k] = Sh[lo]*m + Bh[lo] - 100*pad,
// stored as FP16 (halves traffic; precision ample vs 8.75e-2 threshold).
// Binary search depends only on (b,q,k) -> done ONCE, applied to 8 heads.
// ---------------------------------------------------------------------------
__global__ __launch_bounds__(256) void bias_kernel(
    __half* __restrict__ biasb, const float* __restrict__ rel,
    const float* __restrict__ pad, const float* __restrict__ tsg,
    const float* __restrict__ Stabg, const float* __restrict__ Btabg)
{
  __shared__ float ts[RPEn];
  __shared__ float Sh[(RPEn + 1) * Hn];
  __shared__ float Bh[(RPEn + 1) * Hn];
  const int tid = threadIdx.x;
  const int b = blockIdx.x >> 8, q = blockIdx.x & 255;
  ts[tid] = tsg[tid];
  ts[tid + 256] = tsg[tid + 256];
  for (int i = tid; i < (RPEn + 1) * Hn; i += 256) {
    Sh[i] = Stabg[i];
    Bh[i] = Btabg[i];
  }
  __syncthreads();
#pragma unroll
  for (int j = 0; j < 4; ++j) {
    const int k = tid + j * 256;
    const float m = rel[((size_t)b * NQn + q) * NSn + k];
    const float padv = -100.f * pad[b * NSn + k];
    int lo = 0, hi = RPEn;
#pragma unroll
    for (int it = 0; it < 9; ++it) {
      int mid = (lo + hi) >> 1;
      if (ts[mid] < m) lo = mid + 1; else hi = mid;
    }
#pragma unroll
    for (int h = 0; h < Hn; ++h) {
      biasb[(((size_t)(b * Hn + h)) * NQn + q) * NSn + k] =
          __float2half(Sh[lo * Hn + h] * m + Bh[lo * Hn + h] + padv);
    }
  }
}

// ---------------------------------------------------------------------------
// Flash attention, R=2 rows/thread, HEAD-MAJOR K/V (kT/vT [b][h][k][32]).
// Staging: coalesced gload_lds; rotation swizzle applied on the SOURCE
// address WITHIN each contiguous 128B row: LDS[k][e] = G[k][(e-k)&7].
// Read: unit dd of row k sits at LDS[k][(dd+k)&7] -- swizzle lives entirely
// in ADDRESS arithmetic; register targets q[dd]/o[dd] statically indexed.
// 256 threads = 4 waves; wave w owns rows {2w,2w+1}; lane kc handles keys
// kc, kc+64. Double-buffered; fp16 bias prefetched in registers.
// ---------------------------------------------------------------------------
__global__ __launch_bounds__(256, 2) void flash_kernel(
    float* __restrict__ O, const float* __restrict__ Q,
    const float* __restrict__ kT, const float* __restrict__ vT,
    const __half* __restrict__ biasb, int NK)
{
  __shared__ float4 Ks[2][1024];
  __shared__ float4 Vs[2][1024];
  __shared__ float4 Qs[64];
  const int bh = blockIdx.y, b = bh >> 3, h = bh & 7;
  const int q0 = blockIdx.x * 8;
  const int tid = threadIdx.x;
  const int w = tid >> 6, kc = tid & 63;
  const float4* Ktp = (const float4*)kT + (size_t)bh * NK * 8;
  const float4* Vtp = (const float4*)vT + (size_t)bh * NK * 8;
  if (tid < 64)
    Qs[tid] = ((const float4*)Q)[(size_t)(b * NQn + q0 + (tid >> 3)) * 64 +
                                 h * 8 + (tid & 7)];

  const __half* brow0 =
      biasb ? biasb + ((size_t)bh * NQn + q0 + 2 * w) * NK : nullptr;
  const __half* brow1 = biasb ? brow0 + NK : nullptr;

  // stage chunk at kb0: LDS[k][e] <- G[k][(e-k)&7]. Source is a within-row
  // permutation of a contiguous 16KB block -> coalesced; LDS dest linear.
  auto stage = [&](int buf, int kb0) {
#pragma unroll
    for (int u = 0; u < 4; ++u) {
      const int s = tid + u * 256;   // linear LDS slot (lane order)
      const int k = s >> 3, e = s & 7;
      const int g = (kb0 + k) * 8 + ((e - k) & 7);
      GLDS16(Ktp + g, &Ks[buf][s]);
      GLDS16(Vtp + g, &Vs[buf][s]);
    }
  };

  stage(0, 0);
  float cb[2][2];
  if (biasb) {
    cb[0][0] = __half2float(brow0[kc]);
    cb[0][1] = __half2float(brow0[kc + 64]);
    cb[1][0] = __half2float(brow1[kc]);
    cb[1][1] = __half2float(brow1[kc + 64]);
  }
  __syncthreads();  // drains vmcnt: chunk 0 + Qs ready

  float4 q[2][8];
#pragma unroll
  for (int dd = 0; dd < 8; ++dd) {
    q[0][dd] = Qs[(2 * w) * 8 + dd];
    q[1][dd] = Qs[(2 * w + 1) * 8 + dd];
  }
  float4 o[2][8] = {};
  float m_run[2] = {-3.0e38f, -3.0e38f};
  float l_run[2] = {0.f, 0.f};
  const int nchunk = NK >> 7;

  for (int c = 0; c < nchunk; ++c) {
    const int cur = c & 1;
    float nb[2][2];
    if (c + 1 < nchunk) {
      stage(cur ^ 1, (c + 1) * 128);  // prefetch flies under compute
      if (biasb) {
        nb[0][0] = __half2float(brow0[(c + 1) * 128 + kc]);
        nb[0][1] = __half2float(brow0[(c + 1) * 128 + kc + 64]);
        nb[1][0] = __half2float(brow1[(c + 1) * 128 + kc]);
        nb[1][1] = __half2float(brow1[(c + 1) * 128 + kc + 64]);
      }
    }
    // QK for both rows, keys kc and kc+64 (k&7 == kc&7, rot invariant to j)
    float s[2][2];
#pragma unroll
    for (int j = 0; j < 2; ++j) {
      const int kbase = (kc + j * 64) * 8;
      float4 a0 = {0.f, 0.f, 0.f, 0.f};
      float4 a1 = {0.f, 0.f, 0.f, 0.f};
#pragma unroll
      for (int dd = 0; dd < 8; ++dd) {
        float4 kk = Ks[cur][kbase + ((dd + kc) & 7)];  // = unit dd of row k
        a0.x += q[0][dd].x * kk.x; a0.y += q[0][dd].y * kk.y;
        a0.z += q[0][dd].z * kk.z; a0.w += q[0][dd].w * kk.w;
        a1.x += q[1][dd].x * kk.x; a1.y += q[1][dd].y * kk.y;
        a1.z += q[1][dd].z * kk.z; a1.w += q[1][dd].w * kk.w;
      }
      s[0][j] = (a0.x + a0.y) + (a0.z + a0.w);
      s[1][j] = (a1.x + a1.y) + (a1.z + a1.w);
      if (biasb) { s[0][j] += cb[0][j]; s[1][j] += cb[1][j]; }
    }
    // per-row online softmax update (row's 128 keys live in this wave)
    float f[2];
#pragma unroll
    for (int r = 0; r < 2; ++r) {
      float cmax = fmaxf(s[r][0], s[r][1]);
#pragma unroll
      for (int off = 1; off < 64; off <<= 1)
        cmax = fmaxf(cmax, __shfl_xor(cmax, off));
      const float m_new = fmaxf(m_run[r], cmax);
      f[r] = __expf(m_run[r] - m_new);
      s[r][0] = __expf(s[r][0] - m_new);
      s[r][1] = __expf(s[r][1] - m_new);
      float ls = s[r][0] + s[r][1];
#pragma unroll
      for (int off = 1; off < 64; off <<= 1) ls += __shfl_xor(ls, off);
      l_run[r] = l_run[r] * f[r] + ls;
      m_run[r] = m_new;
    }
#pragma unroll
    for (int dd = 0; dd < 8; ++dd) {
      o[0][dd].x *= f[0]; o[0][dd].y *= f[0]; o[0][dd].z *= f[0]; o[0][dd].w *= f[0];
      o[1][dd].x *= f[1]; o[1][dd].y *= f[1]; o[1][dd].z *= f[1]; o[1][dd].w *= f[1];
    }
    // PV: each V read serves both rows; o statically indexed
#pragma unroll
    for (int j = 0; j < 2; ++j) {
      const int kbase = (kc + j * 64) * 8;
      const float p0 = s[0][j], p1 = s[1][j];
#pragma unroll
      for (int dd = 0; dd < 8; ++dd) {
        float4 vv = Vs[cur][kbase + ((dd + kc) & 7)];  // = unit dd of row k
        o[0][dd].x += p0 * vv.x; o[0][dd].y += p0 * vv.y;
        o[0][dd].z += p0 * vv.z; o[0][dd].w += p0 * vv.w;
        o[1][dd].x += p1 * vv.x; o[1][dd].y += p1 * vv.y;
        o[1][dd].z += p1 * vv.z; o[1][dd].w += p1 * vv.w;
      }
    }
    if (biasb && c + 1 < nchunk) {
      cb[0][0] = nb[0][0]; cb[0][1] = nb[0][1];
      cb[1][0] = nb[1][0]; cb[1][1] = nb[1][1];
    }
    __syncthreads();  // drains prefetch vmcnt + LDS reads before buffer reuse
  }
  // cross-lane o reduction (both rows), then lanes 0/1 write rows 2w/2w+1
#pragma unroll
  for (int off = 1; off < 64; off <<= 1) {
#pragma unroll
    for (int dd = 0; dd < 8; ++dd) {
      o[0][dd].x += __shfl_xor(o[0][dd].x, off);
      o[0][dd].y += __shfl_xor(o[0][dd].y, off);
      o[0][dd].z += __shfl_xor(o[0][dd].z, off);
      o[0][dd].w += __shfl_xor(o[0][dd].w, off);
      o[1][dd].x += __shfl_xor(o[1][dd].x, off);
      o[1][dd].y += __shfl_xor(o[1][dd].y, off);
      o[1][dd].z += __shfl_xor(o[1][dd].z, off);
      o[1][dd].w += __shfl_xor(o[1][dd].w, off);
    }
  }
  if (kc == 0) {
    const float inv = 1.f / l_run[0];
#pragma unroll
    for (int dd = 0; dd < 8; ++dd) {
      float4 v = o[0][dd];
      v.x *= inv; v.y *= inv; v.z *= inv; v.w *= inv;
      ((float4*)O)[(size_t)(b * NQn + q0 + 2 * w) * 64 + h * 8 + dd] = v;
    }
  } else if (kc == 1) {
    const float inv = 1.f / l_run[1];
#pragma unroll
    for (int dd = 0; dd < 8; ++dd) {
      float4 v = o[1][dd];
      v.x *= inv; v.y *= inv; v.z *= inv; v.w *= inv;
      ((float4*)O)[(size_t)(b * NQn + q0 + 2 * w + 1) * 64 + h * 8 + dd] = v;
    }
  }
}

// ---------------------------------------------------------------------------
// gemm64 standalone (FFN1): grid (N/64, M/64), 512 threads.
// ---------------------------------------------------------------------------
__global__ __launch_bounds__(512) void gemm64_kernel(
    float* __restrict__ C, const float* __restrict__ A,
    const float* __restrict__ W, const float* __restrict__ bias,
    int ld, int ldc, int do_relu)
{
  __shared__ float smem[4288];
  float (*As)[33] = (float(*)[33])smem;
  float (*WsT)[68] = (float(*)[68])(smem + 2112);
  gemm64_body(C, ldc, A, nullptr, ld, W, bias, ld,
              blockIdx.y * 64, blockIdx.x * 64, blockIdx.x * 64, 1.f, do_relu,
              0, As, WsT);
}

// ---------------------------------------------------------------------------
// gemm32: 32x32 tile, 256 threads, 2x2/thread, K-step 32, float4 staging with
// register prefetch. Split-K via blockIdx.z (partials at kz*M*N).
// ---------------------------------------------------------------------------
__global__ __launch_bounds__(256) void gemm32_kernel(
    float* __restrict__ C, const float* __restrict__ A, const float* __restrict__ A2,
    const float* __restrict__ W, const float* __restrict__ bias,
    int N, int Kchunk, int Ktot, float scale)
{
  __shared__ float As[32][33];
  __shared__ float Ws[32][33];
  const int bm = blockIdx.y * 32, bn = blockIdx.x * 32;
  const int kz = blockIdx.z;
  const int M = gridDim.y * 32;
  float* Cp = C + (size_t)kz * M * N;
  const int tid = threadIdx.x;
  const int tx = tid & 15, ty = tid >> 4;
  const int lr = tid >> 3, lc = (tid & 7) * 4;
  float acc[2][2] = {};
  const int k00 = kz * Kchunk;
  float4 av, wv;
  {
    av = *(const float4*)(A + (size_t)(bm + lr) * Ktot + k00 + lc);
    if (A2) {
      float4 bv = *(const float4*)(A2 + (size_t)(bm + lr) * Ktot + k00 + lc);
      av.x += bv.x; av.y += bv.y; av.z += bv.z; av.w += bv.w;
    }
    wv = *(const float4*)(W + (size_t)(bn + lr) * Ktot + k00 + lc);
  }
  for (int k0 = k00; k0 < k00 + Kchunk; k0 += 32) {
    As[lr][lc] = av.x; As[lr][lc + 1] = av.y; As[lr][lc + 2] = av.z; As[lr][lc + 3] = av.w;
    Ws[lr][lc] = wv.x; Ws[lr][lc + 1] = wv.y; Ws[lr][lc + 2] = wv.z; Ws[lr][lc + 3] = wv.w;
    __syncthreads();
    if (k0 + 32 < k00 + Kchunk) {
      av = *(const float4*)(A + (size_t)(bm + lr) * Ktot + k0 + 32 + lc);
      if (A2) {
        float4 bv = *(const float4*)(A2 + (size_t)(bm + lr) * Ktot + k0 + 32 + lc);
        av.x += bv.x; av.y += bv.y; av.z += bv.z; av.w += bv.w;
      }
      wv = *(const float4*)(W + (size_t)(bn + lr) * Ktot + k0 + 32 + lc);
    }
#pragma unroll
    for (int k = 0; k < 32; ++k) {
      float a0 = As[ty * 2][k], a1 = As[ty * 2 + 1][k];
      float w0 = Ws[tx * 2][k], w1 = Ws[tx * 2 + 1][k];
      acc[0][0] += a0 * w0; acc[0][1] += a0 * w1;
      acc[1][0] += a1 * w0; acc[1][1] += a1 * w1;
    }
    __syncthreads();
  }
#pragma unroll
  for (int i = 0; i < 2; ++i) {
    int m = bm + ty * 2 + i;
#pragma unroll
    for (int j = 0; j < 2; ++j) {
      int n = bn + tx * 2 + j;
      float v = acc[i][j];
      if (bias) v += bias[n];
      Cp[(size_t)m * N + n] = v * scale;
    }
  }
}

// ---------------------------------------------------------------------------
// out = LayerNorm(x1 + x2) * g + b.  grid: rows, block = 256 = D.
// ---------------------------------------------------------------------------
__global__ __launch_bounds__(256) void add_ln_kernel(
    float* __restrict__ out, const float* __restrict__ x1, const float* __restrict__ x2,
    const float* __restrict__ g, const float* __restrict__ bt)
{
  const int row = blockIdx.x;
  const int t = threadIdx.x;
  const float v = x1[(size_t)row * Dn + t] + x2[(size_t)row * Dn + t];
  float s = v, s2 = v * v;
#pragma unroll
  for (int off = 32; off > 0; off >>= 1) {
    s += __shfl_down(s, off);
    s2 += __shfl_down(s2, off);
  }
  __shared__ float rs[4], rs2[4], fin[2];
  const int lane = t & 63, wid = t >> 6;
  if (lane == 0) { rs[wid] = s; rs2[wid] = s2; }
  __syncthreads();
  if (t == 0) {
    float a = rs[0] + rs[1] + rs[2] + rs[3];
    float a2 = rs2[0] + rs2[1] + rs2[2] + rs2[3];
    float mean = a * (1.f / Dn);
    float var = a2 * (1.f / Dn) - mean * mean;
    fin[0] = mean;
    fin[1] = rsqrtf(var + EPSf);
  }
  __syncthreads();
  out[(size_t)row * Dn + t] = (v - fin[0]) * fin[1] * g[t] + bt[t];
}

// ---------------------------------------------------------------------------
// out = LayerNorm(resid + sum_{kz<4} part[kz] + bias) * g + b (split-K reduce)
// ---------------------------------------------------------------------------
__global__ __launch_bounds__(256) void reduce_ln_kernel(
    float* __restrict__ out, const float* __restrict__ part,
    const float* __restrict__ bias, const float* __restrict__ resid,
    const float* __restrict__ g, const float* __restrict__ bt)
{
  const int row = blockIdx.x;
  const int t = threadIdx.x;
  const size_t idx = (size_t)row * Dn + t;
  const size_t STR = (size_t)Bb * NQn * Dn;
  float v = part[idx] + part[idx + STR] + part[idx + 2 * STR] + part[idx + 3 * STR]
          + bias[t] + resid[idx];
  float s = v, s2 = v * v;
#pragma unroll
  for (int off = 32; off > 0; off >>= 1) {
    s += __shfl_down(s, off);
    s2 += __shfl_down(s2, off);
  }
  __shared__ float rs[4], rs2[4], fin[2];
  const int lane = t & 63, wid = t >> 6;
  if (lane == 0) { rs[wid] = s; rs2[wid] = s2; }
  __syncthreads();
  if (t == 0) {
    float a = rs[0] + rs[1] + rs[2] + rs[3];
    float a2 = rs2[0] + rs2[1] + rs2[2] + rs2[3];
    float mean = a * (1.f / Dn);
    float var = a2 * (1.f / Dn) - mean * mean;
    fin[0] = mean;
    fin[1] = rsqrtf(var + EPSf);
  }
  __syncthreads();
  out[idx] = (v - fin[0]) * fin[1] * g[t] + bt[t];
}

extern "C" void kernel_launch(void* const* d_in, const int* in_sizes, int n_in,
                              void* d_out, int out_size, void* d_ws, size_t ws_size,
                              hipStream_t stream)
{
  const float* tgt   = (const float*)d_in[0];
  const float* qpos  = (const float*)d_in[1];
  const float* src   = (const float*)d_in[2];
  const float* spe   = (const float*)d_in[3];
  const float* pad   = (const float*)d_in[4];
  const float* rel   = (const float*)d_in[5];
  const float* qw    = (const float*)d_in[6];
  const float* qb    = (const float*)d_in[7];
  const float* kw    = (const float*)d_in[8];
  const float* kb    = (const float*)d_in[9];
  const float* vw    = (const float*)d_in[10];
  const float* vb    = (const float*)d_in[11];
  const float* projw = (const float*)d_in[12];
  const float* projb = (const float*)d_in[13];
  const float* cpbw1 = (const float*)d_in[14];
  const float* cpbb1 = (const float*)d_in[15];
  const float* cpbw2 = (const float*)d_in[16];
  const float* ipw   = (const float*)d_in[17];
  const float* ipb   = (const float*)d_in[18];
  const float* outw  = (const float*)d_in[19];
  const float* outb  = (const float*)d_in[20];
  const float* ln1g  = (const float*)d_in[21];
  const float* ln1b  = (const float*)d_in[22];
  const float* ln2g  = (const float*)d_in[23];
  const float* ln2b  = (const float*)d_in[24];
  const float* ln3g  = (const float*)d_in[25];
  const float* ln3b  = (const float*)d_in[26];
  const float* ff1w  = (const float*)d_in[27];
  const float* ff1b  = (const float*)d_in[28];
  const float* ff2w  = (const float*)d_in[29];
  const float* ff2b  = (const float*)d_in[30];
  float* out = (float*)d_out;
  float* ws = (float*)d_ws;

  constexpr size_t SZ_Q   = (size_t)Bb * NQn * Dn;   // 131072
  constexpr size_t SZ_S   = (size_t)Bb * NSn * Dn;   // 524288
  constexpr size_t SZ_FFH = (size_t)Bb * NQn * FFNn; // 524288

  float* qSb  = ws;
  float* kSb  = qSb + SZ_Q;   // head-major kT (self)
  float* vSb  = kSb + SZ_Q;   // head-major vT (self)
  float* oSb  = vSb + SZ_Q;
  float* soP  = oSb + SZ_Q;
  float* tgt2 = soP + SZ_Q;
  float* qCb  = tgt2 + SZ_Q;
  float* kCb  = qCb + SZ_Q;   // head-major kT (cross)
  float* vCb  = kCb + SZ_S;   // head-major vT (cross)
  float* oCb  = vCb + SZ_S;
  float* coP  = oCb + SZ_Q;
  float* tgt3 = coP + SZ_Q;
  float* ffh  = tgt3 + SZ_Q;
  float* part = ffh + SZ_FFH;           // 4 * SZ_Q
  float* tsb  = part + 4 * SZ_Q;
  float* Stab = tsb + RPEn;
  float* Btab = Stab + (RPEn + 1) * Hn;
  __half* biasb = (__half*)(Btab + (RPEn + 1) * Hn);

  const int MQ = Bb * NQn;  // 512

  // 1. prep: cpb tables + self QKV + cross KV (K/V transposed head-major)
  prep_kernel<<<dim3(96 + 256 + 1), dim3(512), 0, stream>>>(
      qSb, kSb, vSb, kCb, vCb, tgt, qpos, src, spe, ipw, ipb,
      kw, kb, vw, vb, cpbw1, cpbb1, cpbw2, tsb, Stab, Btab);

  // 2. materialize cross-attn bias as fp16 (search once per (b,q,k), 8 heads)
  bias_kernel<<<dim3(Bb * NQn), dim3(256), 0, stream>>>(
      biasb, rel, pad, tsb, Stab, Btab);

  // 3. self attention (R=2 flash, coalesced head-major staging)
  flash_kernel<<<dim3(NQn / 8, Bb * Hn), dim3(256), 0, stream>>>(
      oSb, qSb, kSb, vSb, nullptr, NQn);

  // 4. self out-proj
  gemm32_kernel<<<dim3(Dn / 32, MQ / 32, 1), dim3(256), 0, stream>>>(
      soP, oSb, nullptr, outw, outb, Dn, Dn, Dn, 1.f);

  // 5. tgt2 = LN2(tgt + soP)
  add_ln_kernel<<<dim3(MQ), dim3(256), 0, stream>>>(tgt2, tgt, soP, ln2g, ln2b);

  // 6. cross q
  gemm32_kernel<<<dim3(Dn / 32, MQ / 32, 1), dim3(256), 0, stream>>>(
      qCb, tgt2, qpos, qw, qb, Dn, Dn, Dn, SCALEf);

  // 7. cross attention (R=2 flash + fp16 staged bias)
  flash_kernel<<<dim3(NQn / 8, Bb * Hn), dim3(256), 0, stream>>>(
      oCb, qCb, kCb, vCb, biasb, NSn);

  // 8. cross out-proj
  gemm32_kernel<<<dim3(Dn / 32, MQ / 32, 1), dim3(256), 0, stream>>>(
      coP, oCb, nullptr, projw, projb, Dn, Dn, Dn, 1.f);

  // 9. tgt3 = LN1(tgt2 + coP)
  add_ln_kernel<<<dim3(MQ), dim3(256), 0, stream>>>(tgt3, tgt2, coP, ln1g, ln1b);

  // 10. FFN1 (relu)
  gemm64_kernel<<<dim3(FFNn / 64, MQ / 64), dim3(512), 0, stream>>>(
      ffh, tgt3, ff1w, ff1b, Dn, FFNn, 1);

  // 11. FFN2 split-K x4 -> partials
  gemm32_kernel<<<dim3(Dn / 32, MQ / 32, 4), dim3(256), 0, stream>>>(
      part, ffh, nullptr, ff2w, nullptr, Dn, 256, FFNn, 1.f);

  // 12. out = LN3(tgt3 + sum(part) + ff2b)
  reduce_ln_kernel<<<dim3(MQ), dim3(256), 0, stream>>>(
      out, part, ff2b, tgt3, ln3g, ln3b);
}

// Round 14
// 134.083 us; speedup vs baseline: 1.1553x; 1.0089x over previous
//
#include <hip/hip_runtime.h>
#include <hip/hip_bf16.h>
#include <hip/hip_fp16.h>
#include <math.h>

#define Bb 2
#define NQn 256
#define NSn 1024
#define Dn 256
#define Hn 8
#define DHn 32
#define FFNn 1024
#define RPEn 512
#define SCALEf 0.17677669529663687f
#define EPSf 1e-5f

// async global->LDS, 16B per lane. LDS dest must be linear in lane order
// (wave-uniform base + lane*16); global src is per-lane (pre-swizzled).
#define GLDS16(g, l)                                                         \
  __builtin_amdgcn_global_load_lds(                                          \
      (const __attribute__((address_space(1))) void*)(const void*)(g),       \
      (__attribute__((address_space(3))) void*)(void*)(l), 16, 0, 0)

// ---------------------------------------------------------------------------
// gemm64 body: 64x64 tile, 512 threads, K-step 32, float4 loads, reg prefetch.
// trsh != 0: write transposed head-major FP16 Ch[((b*H+h)<<trsh)+kseq][32].
// ---------------------------------------------------------------------------
__device__ __forceinline__ void gemm64_body(
    float* __restrict__ C, __half* __restrict__ Ch, int ldc,
    const float* __restrict__ A, const float* __restrict__ A2, int ld,
    const float* __restrict__ W, const float* __restrict__ bias,
    int K, int bm, int bnC, int bnW, float scale, int do_relu, int trsh,
    float (*As)[33], float (*WsT)[68])
{
  const int tid = threadIdx.x;
  const int tx = tid & 15, ty = tid >> 4;       // ty 0..31
  const int lr = tid >> 3, lc = (tid & 7) * 4;  // staging coords
  float4 ra, rw;
  {
    ra = *(const float4*)(A + (size_t)(bm + lr) * ld + lc);
    if (A2) {
      float4 t = *(const float4*)(A2 + (size_t)(bm + lr) * ld + lc);
      ra.x += t.x; ra.y += t.y; ra.z += t.z; ra.w += t.w;
    }
    rw = *(const float4*)(W + (size_t)(bnW + lr) * ld + lc);
  }
  float acc[2][4] = {};
  for (int k0 = 0; k0 < K; k0 += 32) {
    As[lr][lc] = ra.x; As[lr][lc + 1] = ra.y;
    As[lr][lc + 2] = ra.z; As[lr][lc + 3] = ra.w;
    WsT[lc][lr] = rw.x; WsT[lc + 1][lr] = rw.y;
    WsT[lc + 2][lr] = rw.z; WsT[lc + 3][lr] = rw.w;
    __syncthreads();
    if (k0 + 32 < K) {
      ra = *(const float4*)(A + (size_t)(bm + lr) * ld + k0 + 32 + lc);
      if (A2) {
        float4 t = *(const float4*)(A2 + (size_t)(bm + lr) * ld + k0 + 32 + lc);
        ra.x += t.x; ra.y += t.y; ra.z += t.z; ra.w += t.w;
      }
      rw = *(const float4*)(W + (size_t)(bnW + lr) * ld + k0 + 32 + lc);
    }
#pragma unroll
    for (int k = 0; k < 32; ++k) {
      float a0 = As[ty][k], a1 = As[ty + 32][k];
      float4 w = *(const float4*)&WsT[k][tx * 4];
      acc[0][0] += a0 * w.x; acc[0][1] += a0 * w.y;
      acc[0][2] += a0 * w.z; acc[0][3] += a0 * w.w;
      acc[1][0] += a1 * w.x; acc[1][1] += a1 * w.y;
      acc[1][2] += a1 * w.z; acc[1][3] += a1 * w.w;
    }
    __syncthreads();
  }
#pragma unroll
  for (int i = 0; i < 2; ++i) {
    int m = bm + ty + i * 32;
#pragma unroll
    for (int j = 0; j < 4; ++j) {
      float v = acc[i][j];
      if (bias) v += bias[bnW + tx * 4 + j];
      v *= scale;
      if (do_relu) v = fmaxf(v, 0.f);
      if (trsh == 0) {
        C[(size_t)m * ldc + bnC + tx * 4 + j] = v;
      } else {
        const int nC = bnC + tx * 4 + j;
        const int bb = m >> trsh, kseq = m & ((1 << trsh) - 1);
        const int hh = nC >> 5, d = nC & 31;
        Ch[((((size_t)(bb * Hn + hh)) << trsh) + kseq) * 32 + d] =
            __float2half(v);
      }
    }
  }
}

// ---------------------------------------------------------------------------
// prep: fused build_cpb (1 block) + self QKV GEMM (96 blocks; K/V written
// head-major transposed fp16) + cross KV GEMM (256 blocks). 512 threads.
// ---------------------------------------------------------------------------
__global__ __launch_bounds__(512) void prep_kernel(
    float* __restrict__ qSb, __half* __restrict__ kSb, __half* __restrict__ vSb,
    __half* __restrict__ kCb, __half* __restrict__ vCb,
    const float* __restrict__ tgt, const float* __restrict__ qpos,
    const float* __restrict__ src, const float* __restrict__ spe,
    const float* __restrict__ ipw, const float* __restrict__ ipb,
    const float* __restrict__ kw, const float* __restrict__ kb,
    const float* __restrict__ vw, const float* __restrict__ vb,
    const float* __restrict__ w1p, const float* __restrict__ b1p,
    const float* __restrict__ w2p,
    float* __restrict__ tout, float* __restrict__ Stab, float* __restrict__ Btab)
{
  __shared__ float smem[4288];  // As 64*33=2112 + WsT 32*68=2176
  const int bx = blockIdx.x;
  const int tid = threadIdx.x;
  if (bx < 96) {
    float (*As)[33] = (float(*)[33])smem;
    float (*WsT)[68] = (float(*)[68])(smem + 2112);
    int my = bx & 7, nx = bx >> 3;
    int sec = nx >> 2;
    gemm64_body(qSb, sec == 1 ? kSb : vSb, Dn, tgt,
                sec < 2 ? qpos : nullptr, Dn, ipw, ipb,
                Dn, my * 64, (nx & 3) * 64, nx * 64,
                sec == 0 ? SCALEf : 1.f, 0, sec == 0 ? 0 : 8, As, WsT);
    return;
  }
  if (bx < 96 + 256) {
    float (*As)[33] = (float(*)[33])smem;
    float (*WsT)[68] = (float(*)[68])(smem + 2112);
    int idx = bx - 96;
    int my = idx & 31, nx = idx >> 5;
    int sec = nx >> 2;
    gemm64_body(nullptr, sec ? vCb : kCb, Dn, src, sec ? nullptr : spe, Dn,
                sec ? vw : kw, sec ? vb : kb,
                Dn, my * 64, (nx & 3) * 64, (nx & 3) * 64, 1.f, 0, 10, As, WsT);
    return;
  }
  // ---- cpb piecewise-linear table build (verified rounds 1-13) ----
  float* key = smem;
  int* pidx = (int*)(smem + 512);
  float* w1s = smem + 1024;
  float* b1s = smem + 1536;
  {
    float w = w1p[tid], bb = b1p[tid];
    key[tid] = (w != 0.f) ? (-bb / w) : 3.0e38f;
    pidx[tid] = tid;
  }
  __syncthreads();
  for (int k = 2; k <= RPEn; k <<= 1) {
    for (int j = k >> 1; j > 0; j >>= 1) {
      int ixj = tid ^ j;
      if (ixj > tid) {
        float a = key[tid], c = key[ixj];
        bool asc = ((tid & k) == 0);
        bool sw = asc ? (a > c) : (a < c);
        if (sw) {
          key[tid] = c; key[ixj] = a;
          int tmp = pidx[tid]; pidx[tid] = pidx[ixj]; pidx[ixj] = tmp;
        }
      }
      __syncthreads();
    }
  }
  w1s[tid] = w1p[pidx[tid]];
  b1s[tid] = b1p[pidx[tid]];
  tout[tid] = key[tid];
  __syncthreads();
  const int lane = tid & 63;
  const int h = tid >> 6;
  const int j0 = lane * 8;
  float sp[8], bp[8], sn[8], bn[8];
  float csp = 0.f, cbp = 0.f, csn = 0.f, cbn = 0.f, ccc = 0.f;
#pragma unroll
  for (int e = 0; e < 8; ++e) {
    int j = j0 + e;
    float w = w1s[j], b = b1s[j];
    float c = w2p[h * RPEn + pidx[j]];
    sp[e] = csp; bp[e] = cbp; sn[e] = csn; bn[e] = cbn;
    if (w > 0.f)      { csp += w * c; cbp += b * c; }
    else if (w < 0.f) { csn += w * c; cbn += b * c; }
    else              { ccc += fmaxf(b, 0.f) * c; }
  }
  float isp = csp, ibp = cbp, isn = csn, ibn = cbn, icc = ccc;
#pragma unroll
  for (int d = 1; d < 64; d <<= 1) {
    float t0 = __shfl_up(isp, d);
    float t1 = __shfl_up(ibp, d);
    float t2 = __shfl_up(isn, d);
    float t3 = __shfl_up(ibn, d);
    if (lane >= d) { isp += t0; ibp += t1; isn += t2; ibn += t3; }
    icc += __shfl_xor(icc, d);
  }
  const float tsn = __shfl(isn, 63);
  const float tbn = __shfl(ibn, 63);
  const float esp = isp - csp, ebp = ibp - cbp;
  const float esn = isn - csn, ebn = ibn - cbn;
#pragma unroll
  for (int e = 0; e < 8; ++e) {
    int j = j0 + e;
    Stab[j * Hn + h] = (esp + sp[e]) + (tsn - (esn + sn[e]));
    Btab[j * Hn + h] = (ebp + bp[e]) + (tbn - (ebn + bn[e])) + icc;
  }
  if (lane == 63) {
    Stab[RPEn * Hn + h] = isp;
    Btab[RPEn * Hn + h] = ibp + icc;
  }
}

// ---------------------------------------------------------------------------
// bias_kernel: materialize fp16 bias[b,h,q,k] = Sh[lo]*m + Bh[lo] - 100*pad.
// ---------------------------------------------------------------------------
__global__ __launch_bounds__(256) void bias_kernel(
    __half* __restrict__ biasb, const float* __restrict__ rel,
    const float* __restrict__ pad, const float* __restrict__ tsg,
    const float* __restrict__ Stabg, const float* __restrict__ Btabg)
{
  __shared__ float ts[RPEn];
  __shared__ float Sh[(RPEn + 1) * Hn];
  __shared__ float Bh[(RPEn + 1) * Hn];
  const int tid = threadIdx.x;
  const int b = blockIdx.x >> 8, q = blockIdx.x & 255;
  ts[tid] = tsg[tid];
  ts[tid + 256] = tsg[tid + 256];
  for (int i = tid; i < (RPEn + 1) * Hn; i += 256) {
    Sh[i] = Stabg[i];
    Bh[i] = Btabg[i];
  }
  __syncthreads();
#pragma unroll
  for (int j = 0; j < 4; ++j) {
    const int k = tid + j * 256;
    const float m = rel[((size_t)b * NQn + q) * NSn + k];
    const float padv = -100.f * pad[b * NSn + k];
    int lo = 0, hi = RPEn;
#pragma unroll
    for (int it = 0; it < 9; ++it) {
      int mid = (lo + hi) >> 1;
      if (ts[mid] < m) lo = mid + 1; else hi = mid;
    }
#pragma unroll
    for (int h = 0; h < Hn; ++h) {
      biasb[(((size_t)(b * Hn + h)) * NQn + q) * NSn + k] =
          __float2half(Sh[lo * Hn + h] * m + Bh[lo * Hn + h] + padv);
    }
  }
}

// ---------------------------------------------------------------------------
// Flash attention, R=2 rows/thread, HEAD-MAJOR FP16 K/V (kT/vT [b][h][k][32]).
// K/V rows are 64B = 4 float4 units. Rotation swizzle o(k)=(k+(k>>2))&3 in
// ADDRESS arithmetic only: LDS[k][e] = G[k][(e-o(k))&3]; unit u of row k is
// read from LDS[k][(u+o(k))&3]. Registers statically indexed. Per 16-lane
// phase banks are 2-way (free). Staging fully coalesced contiguous rows.
// 256 threads = 4 waves; wave w owns rows {2w,2w+1}; lane kc keys kc, kc+64.
// Double-buffered gload_lds; fp16 bias prefetched in registers. ~34KB LDS.
// ---------------------------------------------------------------------------
__global__ __launch_bounds__(256, 2) void flash_kernel(
    float* __restrict__ O, const float* __restrict__ Q,
    const __half* __restrict__ kT, const __half* __restrict__ vT,
    const __half* __restrict__ biasb, int NK)
{
  __shared__ float4 Ks[2][512];
  __shared__ float4 Vs[2][512];
  __shared__ float4 Qs[64];
  const int bh = blockIdx.y, b = bh >> 3, h = bh & 7;
  const int q0 = blockIdx.x * 8;
  const int tid = threadIdx.x;
  const int w = tid >> 6, kc = tid & 63;
  const float4* Ktp = (const float4*)kT + (size_t)bh * NK * 4;
  const float4* Vtp = (const float4*)vT + (size_t)bh * NK * 4;
  if (tid < 64)
    Qs[tid] = ((const float4*)Q)[(size_t)(b * NQn + q0 + (tid >> 3)) * 64 +
                                 h * 8 + (tid & 7)];

  const __half* brow0 =
      biasb ? biasb + ((size_t)bh * NQn + q0 + 2 * w) * NK : nullptr;
  const __half* brow1 = biasb ? brow0 + NK : nullptr;

  // stage chunk: LDS[k][e] <- G[k][(e-o(k))&3]; source stays within each
  // contiguous 64B row -> coalesced; LDS dest linear in lane order.
  auto stage = [&](int buf, int kb0) {
#pragma unroll
    for (int u = 0; u < 2; ++u) {
      const int s = tid + u * 256;   // linear LDS slot (lane order)
      const int k = s >> 2, e = s & 3;
      const int ok = (k + (k >> 2)) & 3;
      const int g = (kb0 + k) * 4 + ((e - ok) & 3);
      GLDS16(Ktp + g, &Ks[buf][s]);
      GLDS16(Vtp + g, &Vs[buf][s]);
    }
  };

  stage(0, 0);
  float cb[2][2];
  if (biasb) {
    cb[0][0] = __half2float(brow0[kc]);
    cb[0][1] = __half2float(brow0[kc + 64]);
    cb[1][0] = __half2float(brow1[kc]);
    cb[1][1] = __half2float(brow1[kc + 64]);
  }
  __syncthreads();  // drains vmcnt: chunk 0 + Qs ready

  float4 q[2][8];
#pragma unroll
  for (int dd = 0; dd < 8; ++dd) {
    q[0][dd] = Qs[(2 * w) * 8 + dd];
    q[1][dd] = Qs[(2 * w + 1) * 8 + dd];
  }
  float4 o[2][8] = {};
  float m_run[2] = {-3.0e38f, -3.0e38f};
  float l_run[2] = {0.f, 0.f};
  const int nchunk = NK >> 7;
  // row-rotation key: same for kc and kc+64 ((64 + 16) % 4 == 0)
  const int ox = (kc + (kc >> 2)) & 3;

  for (int c = 0; c < nchunk; ++c) {
    const int cur = c & 1;
    float nb[2][2];
    if (c + 1 < nchunk) {
      stage(cur ^ 1, (c + 1) * 128);  // prefetch flies under compute
      if (biasb) {
        nb[0][0] = __half2float(brow0[(c + 1) * 128 + kc]);
        nb[0][1] = __half2float(brow0[(c + 1) * 128 + kc + 64]);
        nb[1][0] = __half2float(brow1[(c + 1) * 128 + kc]);
        nb[1][1] = __half2float(brow1[(c + 1) * 128 + kc + 64]);
      }
    }
    // QK for both rows, keys kc and kc+64; fp16 K converted once per key row
    float s[2][2];
#pragma unroll
    for (int j = 0; j < 2; ++j) {
      const int kbase = (kc + j * 64) * 4;
      float a0 = 0.f, a1 = 0.f;
#pragma unroll
      for (int u = 0; u < 4; ++u) {
        float4 raw = Ks[cur][kbase + ((u + ox) & 3)];  // = unit u of row k
        const __half2* hp = (const __half2*)&raw;
        float2 f0 = __half22float2(hp[0]);
        float2 f1 = __half22float2(hp[1]);
        float2 f2 = __half22float2(hp[2]);
        float2 f3 = __half22float2(hp[3]);
        a0 += q[0][2 * u].x * f0.x + q[0][2 * u].y * f0.y +
              q[0][2 * u].z * f1.x + q[0][2 * u].w * f1.y +
              q[0][2 * u + 1].x * f2.x + q[0][2 * u + 1].y * f2.y +
              q[0][2 * u + 1].z * f3.x + q[0][2 * u + 1].w * f3.y;
        a1 += q[1][2 * u].x * f0.x + q[1][2 * u].y * f0.y +
              q[1][2 * u].z * f1.x + q[1][2 * u].w * f1.y +
              q[1][2 * u + 1].x * f2.x + q[1][2 * u + 1].y * f2.y +
              q[1][2 * u + 1].z * f3.x + q[1][2 * u + 1].w * f3.y;
      }
      s[0][j] = a0;
      s[1][j] = a1;
      if (biasb) { s[0][j] += cb[0][j]; s[1][j] += cb[1][j]; }
    }
    // per-row online softmax update (row's 128 keys live in this wave)
    float f[2];
#pragma unroll
    for (int r = 0; r < 2; ++r) {
      float cmax = fmaxf(s[r][0], s[r][1]);
#pragma unroll
      for (int off = 1; off < 64; off <<= 1)
        cmax = fmaxf(cmax, __shfl_xor(cmax, off));
      const float m_new = fmaxf(m_run[r], cmax);
      f[r] = __expf(m_run[r] - m_new);
      s[r][0] = __expf(s[r][0] - m_new);
      s[r][1] = __expf(s[r][1] - m_new);
      float ls = s[r][0] + s[r][1];
#pragma unroll
      for (int off = 1; off < 64; off <<= 1) ls += __shfl_xor(ls, off);
      l_run[r] = l_run[r] * f[r] + ls;
      m_run[r] = m_new;
    }
#pragma unroll
    for (int dd = 0; dd < 8; ++dd) {
      o[0][dd].x *= f[0]; o[0][dd].y *= f[0]; o[0][dd].z *= f[0]; o[0][dd].w *= f[0];
      o[1][dd].x *= f[1]; o[1][dd].y *= f[1]; o[1][dd].z *= f[1]; o[1][dd].w *= f[1];
    }
    // PV: each fp16 V read converted once, serves both rows; o static-indexed
#pragma unroll
    for (int j = 0; j < 2; ++j) {
      const int kbase = (kc + j * 64) * 4;
      const float p0 = s[0][j], p1 = s[1][j];
#pragma unroll
      for (int u = 0; u < 4; ++u) {
        float4 raw = Vs[cur][kbase + ((u + ox) & 3)];  // = unit u of row k
        const __half2* hp = (const __half2*)&raw;
        float2 f0 = __half22float2(hp[0]);
        float2 f1 = __half22float2(hp[1]);
        float2 f2 = __half22float2(hp[2]);
        float2 f3 = __half22float2(hp[3]);
        o[0][2 * u].x += p0 * f0.x; o[0][2 * u].y += p0 * f0.y;
        o[0][2 * u].z += p0 * f1.x; o[0][2 * u].w += p0 * f1.y;
        o[0][2 * u + 1].x += p0 * f2.x; o[0][2 * u + 1].y += p0 * f2.y;
        o[0][2 * u + 1].z += p0 * f3.x; o[0][2 * u + 1].w += p0 * f3.y;
        o[1][2 * u].x += p1 * f0.x; o[1][2 * u].y += p1 * f0.y;
        o[1][2 * u].z += p1 * f1.x; o[1][2 * u].w += p1 * f1.y;
        o[1][2 * u + 1].x += p1 * f2.x; o[1][2 * u + 1].y += p1 * f2.y;
        o[1][2 * u + 1].z += p1 * f3.x; o[1][2 * u + 1].w += p1 * f3.y;
      }
    }
    if (biasb && c + 1 < nchunk) {
      cb[0][0] = nb[0][0]; cb[0][1] = nb[0][1];
      cb[1][0] = nb[1][0]; cb[1][1] = nb[1][1];
    }
    __syncthreads();  // drains prefetch vmcnt + LDS reads before buffer reuse
  }
  // cross-lane o reduction (both rows), then lanes 0/1 write rows 2w/2w+1
#pragma unroll
  for (int off = 1; off < 64; off <<= 1) {
#pragma unroll
    for (int dd = 0; dd < 8; ++dd) {
      o[0][dd].x += __shfl_xor(o[0][dd].x, off);
      o[0][dd].y += __shfl_xor(o[0][dd].y, off);
      o[0][dd].z += __shfl_xor(o[0][dd].z, off);
      o[0][dd].w += __shfl_xor(o[0][dd].w, off);
      o[1][dd].x += __shfl_xor(o[1][dd].x, off);
      o[1][dd].y += __shfl_xor(o[1][dd].y, off);
      o[1][dd].z += __shfl_xor(o[1][dd].z, off);
      o[1][dd].w += __shfl_xor(o[1][dd].w, off);
    }
  }
  if (kc == 0) {
    const float inv = 1.f / l_run[0];
#pragma unroll
    for (int dd = 0; dd < 8; ++dd) {
      float4 v = o[0][dd];
      v.x *= inv; v.y *= inv; v.z *= inv; v.w *= inv;
      ((float4*)O)[(size_t)(b * NQn + q0 + 2 * w) * 64 + h * 8 + dd] = v;
    }
  } else if (kc == 1) {
    const float inv = 1.f / l_run[1];
#pragma unroll
    for (int dd = 0; dd < 8; ++dd) {
      float4 v = o[1][dd];
      v.x *= inv; v.y *= inv; v.z *= inv; v.w *= inv;
      ((float4*)O)[(size_t)(b * NQn + q0 + 2 * w + 1) * 64 + h * 8 + dd] = v;
    }
  }
}

// ---------------------------------------------------------------------------
// gemm64 standalone (FFN1): grid (N/64, M/64), 512 threads.
// ---------------------------------------------------------------------------
__global__ __launch_bounds__(512) void gemm64_kernel(
    float* __restrict__ C, const float* __restrict__ A,
    const float* __restrict__ W, const float* __restrict__ bias,
    int ld, int ldc, int do_relu)
{
  __shared__ float smem[4288];
  float (*As)[33] = (float(*)[33])smem;
  float (*WsT)[68] = (float(*)[68])(smem + 2112);
  gemm64_body(C, nullptr, ldc, A, nullptr, ld, W, bias, ld,
              blockIdx.y * 64, blockIdx.x * 64, blockIdx.x * 64, 1.f, do_relu,
              0, As, WsT);
}

// ---------------------------------------------------------------------------
// gemm32: 32x32 tile, 256 threads, 2x2/thread, K-step 32, float4 staging with
// register prefetch. Split-K via blockIdx.z (partials at kz*M*N).
// ---------------------------------------------------------------------------
__global__ __launch_bounds__(256) void gemm32_kernel(
    float* __restrict__ C, const float* __restrict__ A, const float* __restrict__ A2,
    const float* __restrict__ W, const float* __restrict__ bias,
    int N, int Kchunk, int Ktot, float scale)
{
  __shared__ float As[32][33];
  __shared__ float Ws[32][33];
  const int bm = blockIdx.y * 32, bn = blockIdx.x * 32;
  const int kz = blockIdx.z;
  const int M = gridDim.y * 32;
  float* Cp = C + (size_t)kz * M * N;
  const int tid = threadIdx.x;
  const int tx = tid & 15, ty = tid >> 4;
  const int lr = tid >> 3, lc = (tid & 7) * 4;
  float acc[2][2] = {};
  const int k00 = kz * Kchunk;
  float4 av, wv;
  {
    av = *(const float4*)(A + (size_t)(bm + lr) * Ktot + k00 + lc);
    if (A2) {
      float4 bv = *(const float4*)(A2 + (size_t)(bm + lr) * Ktot + k00 + lc);
      av.x += bv.x; av.y += bv.y; av.z += bv.z; av.w += bv.w;
    }
    wv = *(const float4*)(W + (size_t)(bn + lr) * Ktot + k00 + lc);
  }
  for (int k0 = k00; k0 < k00 + Kchunk; k0 += 32) {
    As[lr][lc] = av.x; As[lr][lc + 1] = av.y; As[lr][lc + 2] = av.z; As[lr][lc + 3] = av.w;
    Ws[lr][lc] = wv.x; Ws[lr][lc + 1] = wv.y; Ws[lr][lc + 2] = wv.z; Ws[lr][lc + 3] = wv.w;
    __syncthreads();
    if (k0 + 32 < k00 + Kchunk) {
      av = *(const float4*)(A + (size_t)(bm + lr) * Ktot + k0 + 32 + lc);
      if (A2) {
        float4 bv = *(const float4*)(A2 + (size_t)(bm + lr) * Ktot + k0 + 32 + lc);
        av.x += bv.x; av.y += bv.y; av.z += bv.z; av.w += bv.w;
      }
      wv = *(const float4*)(W + (size_t)(bn + lr) * Ktot + k0 + 32 + lc);
    }
#pragma unroll
    for (int k = 0; k < 32; ++k) {
      float a0 = As[ty * 2][k], a1 = As[ty * 2 + 1][k];
      float w0 = Ws[tx * 2][k], w1 = Ws[tx * 2 + 1][k];
      acc[0][0] += a0 * w0; acc[0][1] += a0 * w1;
      acc[1][0] += a1 * w0; acc[1][1] += a1 * w1;
    }
    __syncthreads();
  }
#pragma unroll
  for (int i = 0; i < 2; ++i) {
    int m = bm + ty * 2 + i;
#pragma unroll
    for (int j = 0; j < 2; ++j) {
      int n = bn + tx * 2 + j;
      float v = acc[i][j];
      if (bias) v += bias[n];
      Cp[(size_t)m * N + n] = v * scale;
    }
  }
}

// ---------------------------------------------------------------------------
// out = LayerNorm(x1 + x2) * g + b.  grid: rows, block = 256 = D.
// ---------------------------------------------------------------------------
__global__ __launch_bounds__(256) void add_ln_kernel(
    float* __restrict__ out, const float* __restrict__ x1, const float* __restrict__ x2,
    const float* __restrict__ g, const float* __restrict__ bt)
{
  const int row = blockIdx.x;
  const int t = threadIdx.x;
  const float v = x1[(size_t)row * Dn + t] + x2[(size_t)row * Dn + t];
  float s = v, s2 = v * v;
#pragma unroll
  for (int off = 32; off > 0; off >>= 1) {
    s += __shfl_down(s, off);
    s2 += __shfl_down(s2, off);
  }
  __shared__ float rs[4], rs2[4], fin[2];
  const int lane = t & 63, wid = t >> 6;
  if (lane == 0) { rs[wid] = s; rs2[wid] = s2; }
  __syncthreads();
  if (t == 0) {
    float a = rs[0] + rs[1] + rs[2] + rs[3];
    float a2 = rs2[0] + rs2[1] + rs2[2] + rs2[3];
    float mean = a * (1.f / Dn);
    float var = a2 * (1.f / Dn) - mean * mean;
    fin[0] = mean;
    fin[1] = rsqrtf(var + EPSf);
  }
  __syncthreads();
  out[(size_t)row * Dn + t] = (v - fin[0]) * fin[1] * g[t] + bt[t];
}

// ---------------------------------------------------------------------------
// out = LayerNorm(resid + sum_{kz<4} part[kz] + bias) * g + b (split-K reduce)
// ---------------------------------------------------------------------------
__global__ __launch_bounds__(256) void reduce_ln_kernel(
    float* __restrict__ out, const float* __restrict__ part,
    const float* __restrict__ bias, const float* __restrict__ resid,
    const float* __restrict__ g, const float* __restrict__ bt)
{
  const int row = blockIdx.x;
  const int t = threadIdx.x;
  const size_t idx = (size_t)row * Dn + t;
  const size_t STR = (size_t)Bb * NQn * Dn;
  float v = part[idx] + part[idx + STR] + part[idx + 2 * STR] + part[idx + 3 * STR]
          + bias[t] + resid[idx];
  float s = v, s2 = v * v;
#pragma unroll
  for (int off = 32; off > 0; off >>= 1) {
    s += __shfl_down(s, off);
    s2 += __shfl_down(s2, off);
  }
  __shared__ float rs[4], rs2[4], fin[2];
  const int lane = t & 63, wid = t >> 6;
  if (lane == 0) { rs[wid] = s; rs2[wid] = s2; }
  __syncthreads();
  if (t == 0) {
    float a = rs[0] + rs[1] + rs[2] + rs[3];
    float a2 = rs2[0] + rs2[1] + rs2[2] + rs2[3];
    float mean = a * (1.f / Dn);
    float var = a2 * (1.f / Dn) - mean * mean;
    fin[0] = mean;
    fin[1] = rsqrtf(var + EPSf);
  }
  __syncthreads();
  out[idx] = (v - fin[0]) * fin[1] * g[t] + bt[t];
}

extern "C" void kernel_launch(void* const* d_in, const int* in_sizes, int n_in,
                              void* d_out, int out_size, void* d_ws, size_t ws_size,
                              hipStream_t stream)
{
  const float* tgt   = (const float*)d_in[0];
  const float* qpos  = (const float*)d_in[1];
  const float* src   = (const float*)d_in[2];
  const float* spe   = (const float*)d_in[3];
  const float* pad   = (const float*)d_in[4];
  const float* rel   = (const float*)d_in[5];
  const float* qw    = (const float*)d_in[6];
  const float* qb    = (const float*)d_in[7];
  const float* kw    = (const float*)d_in[8];
  const float* kb    = (const float*)d_in[9];
  const float* vw    = (const float*)d_in[10];
  const float* vb    = (const float*)d_in[11];
  const float* projw = (const float*)d_in[12];
  const float* projb = (const float*)d_in[13];
  const float* cpbw1 = (const float*)d_in[14];
  const float* cpbb1 = (const float*)d_in[15];
  const float* cpbw2 = (const float*)d_in[16];
  const float* ipw   = (const float*)d_in[17];
  const float* ipb   = (const float*)d_in[18];
  const float* outw  = (const float*)d_in[19];
  const float* outb  = (const float*)d_in[20];
  const float* ln1g  = (const float*)d_in[21];
  const float* ln1b  = (const float*)d_in[22];
  const float* ln2g  = (const float*)d_in[23];
  const float* ln2b  = (const float*)d_in[24];
  const float* ln3g  = (const float*)d_in[25];
  const float* ln3b  = (const float*)d_in[26];
  const float* ff1w  = (const float*)d_in[27];
  const float* ff1b  = (const float*)d_in[28];
  const float* ff2w  = (const float*)d_in[29];
  const float* ff2b  = (const float*)d_in[30];
  float* out = (float*)d_out;
  float* ws = (float*)d_ws;

  constexpr size_t SZ_Q   = (size_t)Bb * NQn * Dn;   // 131072
  constexpr size_t SZ_S   = (size_t)Bb * NSn * Dn;   // 524288
  constexpr size_t SZ_FFH = (size_t)Bb * NQn * FFNn; // 524288

  float* qSb  = ws;
  __half* kSb = (__half*)(qSb + SZ_Q);   // head-major fp16 kT (self)
  __half* vSb = (__half*)(qSb + 2 * SZ_Q);
  float* oSb  = ws + 3 * SZ_Q;
  float* soP  = oSb + SZ_Q;
  float* tgt2 = soP + SZ_Q;
  float* qCb  = tgt2 + SZ_Q;
  __half* kCb = (__half*)(qCb + SZ_Q);   // head-major fp16 kT (cross)
  __half* vCb = (__half*)(qCb + SZ_Q + SZ_S);
  float* oCb  = qCb + SZ_Q + 2 * SZ_S;
  float* coP  = oCb + SZ_Q;
  float* tgt3 = coP + SZ_Q;
  float* ffh  = tgt3 + SZ_Q;
  float* part = ffh + SZ_FFH;           // 4 * SZ_Q
  float* tsb  = part + 4 * SZ_Q;
  float* Stab = tsb + RPEn;
  float* Btab = Stab + (RPEn + 1) * Hn;
  __half* biasb = (__half*)(Btab + (RPEn + 1) * Hn);

  const int MQ = Bb * NQn;  // 512

  // 1. prep: cpb tables + self QKV + cross KV (K/V transposed fp16 head-major)
  prep_kernel<<<dim3(96 + 256 + 1), dim3(512), 0, stream>>>(
      qSb, kSb, vSb, kCb, vCb, tgt, qpos, src, spe, ipw, ipb,
      kw, kb, vw, vb, cpbw1, cpbb1, cpbw2, tsb, Stab, Btab);

  // 2. materialize cross-attn bias as fp16 (search once per (b,q,k), 8 heads)
  bias_kernel<<<dim3(Bb * NQn), dim3(256), 0, stream>>>(
      biasb, rel, pad, tsb, Stab, Btab);

  // 3. self attention (R=2 flash, fp16 K/V)
  flash_kernel<<<dim3(NQn / 8, Bb * Hn), dim3(256), 0, stream>>>(
      oSb, qSb, kSb, vSb, nullptr, NQn);

  // 4. self out-proj
  gemm32_kernel<<<dim3(Dn / 32, MQ / 32, 1), dim3(256), 0, stream>>>(
      soP, oSb, nullptr, outw, outb, Dn, Dn, Dn, 1.f);

  // 5. tgt2 = LN2(tgt + soP)
  add_ln_kernel<<<dim3(MQ), dim3(256), 0, stream>>>(tgt2, tgt, soP, ln2g, ln2b);

  // 6. cross q
  gemm32_kernel<<<dim3(Dn / 32, MQ / 32, 1), dim3(256), 0, stream>>>(
      qCb, tgt2, qpos, qw, qb, Dn, Dn, Dn, SCALEf);

  // 7. cross attention (R=2 flash, fp16 K/V + fp16 staged bias)
  flash_kernel<<<dim3(NQn / 8, Bb * Hn), dim3(256), 0, stream>>>(
      oCb, qCb, kCb, vCb, biasb, NSn);

  // 8. cross out-proj
  gemm32_kernel<<<dim3(Dn / 32, MQ / 32, 1), dim3(256), 0, stream>>>(
      coP, oCb, nullptr, projw, projb, Dn, Dn, Dn, 1.f);

  // 9. tgt3 = LN1(tgt2 + coP)
  add_ln_kernel<<<dim3(MQ), dim3(256), 0, stream>>>(tgt3, tgt2, coP, ln1g, ln1b);

  // 10. FFN1 (relu)
  gemm64_kernel<<<dim3(FFNn / 64, MQ / 64), dim3(512), 0, stream>>>(
      ffh, tgt3, ff1w, ff1b, Dn, FFNn, 1);

  // 11. FFN2 split-K x4 -> partials
  gemm32_kernel<<<dim3(Dn / 32, MQ / 32, 4), dim3(256), 0, stream>>>(
      part, ffh, nullptr, ff2w, nullptr, Dn, 256, FFNn, 1.f);

  // 12. out = LN3(tgt3 + sum(part) + ff2b)
  reduce_ln_kernel<<<dim3(MQ), dim3(256), 0, stream>>>(
      out, part, ff2b, tgt3, ln3g, ln3b);
}

// Round 15
// 129.090 us; speedup vs baseline: 1.1999x; 1.0387x over previous
//
#include <hip/hip_runtime.h>
#include <hip/hip_bf16.h>
#include <hip/hip_fp16.h>
#include <math.h>

#define Bb 2
#define NQn 256
#define NSn 1024
#define Dn 256
#define Hn 8
#define DHn 32
#define FFNn 1024
#define RPEn 512
#define SCALEf 0.17677669529663687f
#define EPSf 1e-5f

// async global->LDS, 16B per lane. LDS dest must be linear in lane order
// (wave-uniform base + lane*16); global src is per-lane (pre-swizzled).
#define GLDS16(g, l)                                                         \
  __builtin_amdgcn_global_load_lds(                                          \
      (const __attribute__((address_space(1))) void*)(const void*)(g),       \
      (__attribute__((address_space(3))) void*)(void*)(l), 16, 0, 0)

// ---------------------------------------------------------------------------
// gemm64 body: 64x64 tile, 512 threads, K-step 32, float4 loads, reg prefetch.
// trsh != 0: write transposed head-major FP16 Ch[((b*H+h)<<trsh)+kseq][32].
// ---------------------------------------------------------------------------
__device__ __forceinline__ void gemm64_body(
    float* __restrict__ C, __half* __restrict__ Ch, int ldc,
    const float* __restrict__ A, const float* __restrict__ A2, int ld,
    const float* __restrict__ W, const float* __restrict__ bias,
    int K, int bm, int bnC, int bnW, float scale, int do_relu, int trsh,
    float (*As)[33], float (*WsT)[68])
{
  const int tid = threadIdx.x;
  const int tx = tid & 15, ty = tid >> 4;       // ty 0..31
  const int lr = tid >> 3, lc = (tid & 7) * 4;  // staging coords
  float4 ra, rw;
  {
    ra = *(const float4*)(A + (size_t)(bm + lr) * ld + lc);
    if (A2) {
      float4 t = *(const float4*)(A2 + (size_t)(bm + lr) * ld + lc);
      ra.x += t.x; ra.y += t.y; ra.z += t.z; ra.w += t.w;
    }
    rw = *(const float4*)(W + (size_t)(bnW + lr) * ld + lc);
  }
  float acc[2][4] = {};
  for (int k0 = 0; k0 < K; k0 += 32) {
    As[lr][lc] = ra.x; As[lr][lc + 1] = ra.y;
    As[lr][lc + 2] = ra.z; As[lr][lc + 3] = ra.w;
    WsT[lc][lr] = rw.x; WsT[lc + 1][lr] = rw.y;
    WsT[lc + 2][lr] = rw.z; WsT[lc + 3][lr] = rw.w;
    __syncthreads();
    if (k0 + 32 < K) {
      ra = *(const float4*)(A + (size_t)(bm + lr) * ld + k0 + 32 + lc);
      if (A2) {
        float4 t = *(const float4*)(A2 + (size_t)(bm + lr) * ld + k0 + 32 + lc);
        ra.x += t.x; ra.y += t.y; ra.z += t.z; ra.w += t.w;
      }
      rw = *(const float4*)(W + (size_t)(bnW + lr) * ld + k0 + 32 + lc);
    }
#pragma unroll
    for (int k = 0; k < 32; ++k) {
      float a0 = As[ty][k], a1 = As[ty + 32][k];
      float4 w = *(const float4*)&WsT[k][tx * 4];
      acc[0][0] += a0 * w.x; acc[0][1] += a0 * w.y;
      acc[0][2] += a0 * w.z; acc[0][3] += a0 * w.w;
      acc[1][0] += a1 * w.x; acc[1][1] += a1 * w.y;
      acc[1][2] += a1 * w.z; acc[1][3] += a1 * w.w;
    }
    __syncthreads();
  }
#pragma unroll
  for (int i = 0; i < 2; ++i) {
    int m = bm + ty + i * 32;
#pragma unroll
    for (int j = 0; j < 4; ++j) {
      float v = acc[i][j];
      if (bias) v += bias[bnW + tx * 4 + j];
      v *= scale;
      if (do_relu) v = fmaxf(v, 0.f);
      if (trsh == 0) {
        C[(size_t)m * ldc + bnC + tx * 4 + j] = v;
      } else {
        const int nC = bnC + tx * 4 + j;
        const int bb = m >> trsh, kseq = m & ((1 << trsh) - 1);
        const int hh = nC >> 5, d = nC & 31;
        Ch[((((size_t)(bb * Hn + hh)) << trsh) + kseq) * 32 + d] =
            __float2half(v);
      }
    }
  }
}

// ---------------------------------------------------------------------------
// prep: fused build_cpb (1 block) + self QKV GEMM (96 blocks; K/V written
// head-major transposed fp16) + cross KV GEMM (256 blocks). 512 threads.
// ---------------------------------------------------------------------------
__global__ __launch_bounds__(512) void prep_kernel(
    float* __restrict__ qSb, __half* __restrict__ kSb, __half* __restrict__ vSb,
    __half* __restrict__ kCb, __half* __restrict__ vCb,
    const float* __restrict__ tgt, const float* __restrict__ qpos,
    const float* __restrict__ src, const float* __restrict__ spe,
    const float* __restrict__ ipw, const float* __restrict__ ipb,
    const float* __restrict__ kw, const float* __restrict__ kb,
    const float* __restrict__ vw, const float* __restrict__ vb,
    const float* __restrict__ w1p, const float* __restrict__ b1p,
    const float* __restrict__ w2p,
    float* __restrict__ tout, float* __restrict__ Stab, float* __restrict__ Btab)
{
  __shared__ float smem[4288];  // As 64*33=2112 + WsT 32*68=2176
  const int bx = blockIdx.x;
  const int tid = threadIdx.x;
  if (bx < 96) {
    float (*As)[33] = (float(*)[33])smem;
    float (*WsT)[68] = (float(*)[68])(smem + 2112);
    int my = bx & 7, nx = bx >> 3;
    int sec = nx >> 2;
    gemm64_body(qSb, sec == 1 ? kSb : vSb, Dn, tgt,
                sec < 2 ? qpos : nullptr, Dn, ipw, ipb,
                Dn, my * 64, (nx & 3) * 64, nx * 64,
                sec == 0 ? SCALEf : 1.f, 0, sec == 0 ? 0 : 8, As, WsT);
    return;
  }
  if (bx < 96 + 256) {
    float (*As)[33] = (float(*)[33])smem;
    float (*WsT)[68] = (float(*)[68])(smem + 2112);
    int idx = bx - 96;
    int my = idx & 31, nx = idx >> 5;
    int sec = nx >> 2;
    gemm64_body(nullptr, sec ? vCb : kCb, Dn, src, sec ? nullptr : spe, Dn,
                sec ? vw : kw, sec ? vb : kb,
                Dn, my * 64, (nx & 3) * 64, (nx & 3) * 64, 1.f, 0, 10, As, WsT);
    return;
  }
  // ---- cpb piecewise-linear table build (verified rounds 1-14) ----
  float* key = smem;
  int* pidx = (int*)(smem + 512);
  float* w1s = smem + 1024;
  float* b1s = smem + 1536;
  {
    float w = w1p[tid], bb = b1p[tid];
    key[tid] = (w != 0.f) ? (-bb / w) : 3.0e38f;
    pidx[tid] = tid;
  }
  __syncthreads();
  for (int k = 2; k <= RPEn; k <<= 1) {
    for (int j = k >> 1; j > 0; j >>= 1) {
      int ixj = tid ^ j;
      if (ixj > tid) {
        float a = key[tid], c = key[ixj];
        bool asc = ((tid & k) == 0);
        bool sw = asc ? (a > c) : (a < c);
        if (sw) {
          key[tid] = c; key[ixj] = a;
          int tmp = pidx[tid]; pidx[tid] = pidx[ixj]; pidx[ixj] = tmp;
        }
      }
      __syncthreads();
    }
  }
  w1s[tid] = w1p[pidx[tid]];
  b1s[tid] = b1p[pidx[tid]];
  tout[tid] = key[tid];
  __syncthreads();
  const int lane = tid & 63;
  const int h = tid >> 6;
  const int j0 = lane * 8;
  float sp[8], bp[8], sn[8], bn[8];
  float csp = 0.f, cbp = 0.f, csn = 0.f, cbn = 0.f, ccc = 0.f;
#pragma unroll
  for (int e = 0; e < 8; ++e) {
    int j = j0 + e;
    float w = w1s[j], b = b1s[j];
    float c = w2p[h * RPEn + pidx[j]];
    sp[e] = csp; bp[e] = cbp; sn[e] = csn; bn[e] = cbn;
    if (w > 0.f)      { csp += w * c; cbp += b * c; }
    else if (w < 0.f) { csn += w * c; cbn += b * c; }
    else              { ccc += fmaxf(b, 0.f) * c; }
  }
  float isp = csp, ibp = cbp, isn = csn, ibn = cbn, icc = ccc;
#pragma unroll
  for (int d = 1; d < 64; d <<= 1) {
    float t0 = __shfl_up(isp, d);
    float t1 = __shfl_up(ibp, d);
    float t2 = __shfl_up(isn, d);
    float t3 = __shfl_up(ibn, d);
    if (lane >= d) { isp += t0; ibp += t1; isn += t2; ibn += t3; }
    icc += __shfl_xor(icc, d);
  }
  const float tsn = __shfl(isn, 63);
  const float tbn = __shfl(ibn, 63);
  const float esp = isp - csp, ebp = ibp - cbp;
  const float esn = isn - csn, ebn = ibn - cbn;
#pragma unroll
  for (int e = 0; e < 8; ++e) {
    int j = j0 + e;
    Stab[j * Hn + h] = (esp + sp[e]) + (tsn - (esn + sn[e]));
    Btab[j * Hn + h] = (ebp + bp[e]) + (tbn - (ebn + bn[e])) + icc;
  }
  if (lane == 63) {
    Stab[RPEn * Hn + h] = isp;
    Btab[RPEn * Hn + h] = ibp + icc;
  }
}

// ---------------------------------------------------------------------------
// bias body: fp16 bias[b,h,q,k] = Sh[lo]*m + Bh[lo] - 100*pad. One block per
// (b,q); search once per (b,q,k), applied to 8 heads. LDS carved from smem.
// ---------------------------------------------------------------------------
__device__ __forceinline__ void bias_body(
    char* smemraw, int idx,
    __half* __restrict__ biasb, const float* __restrict__ rel,
    const float* __restrict__ pad, const float* __restrict__ tsg,
    const float* __restrict__ Stabg, const float* __restrict__ Btabg)
{
  float* ts = (float*)smemraw;                    // 512 f
  float* Sh = (float*)(smemraw + 2048);           // 4104 f
  float* Bh = (float*)(smemraw + 18464);          // 4104 f
  const int tid = threadIdx.x;
  const int b = idx >> 8, q = idx & 255;
  ts[tid] = tsg[tid];
  ts[tid + 256] = tsg[tid + 256];
  for (int i = tid; i < (RPEn + 1) * Hn; i += 256) {
    Sh[i] = Stabg[i];
    Bh[i] = Btabg[i];
  }
  __syncthreads();
#pragma unroll
  for (int j = 0; j < 4; ++j) {
    const int k = tid + j * 256;
    const float m = rel[((size_t)b * NQn + q) * NSn + k];
    const float padv = -100.f * pad[b * NSn + k];
    int lo = 0, hi = RPEn;
#pragma unroll
    for (int it = 0; it < 9; ++it) {
      int mid = (lo + hi) >> 1;
      if (ts[mid] < m) lo = mid + 1; else hi = mid;
    }
#pragma unroll
    for (int h = 0; h < Hn; ++h) {
      biasb[(((size_t)(b * Hn + h)) * NQn + q) * NSn + k] =
          __float2half(Sh[lo * Hn + h] * m + Bh[lo * Hn + h] + padv);
    }
  }
}

// ---------------------------------------------------------------------------
// Flash body (verified round 14): R=2 rows/thread, HEAD-MAJOR FP16 K/V
// (kT/vT [b][h][k][32], rows = 64B = 4 float4 units). Rotation swizzle
// o(k)=(k+(k>>2))&3 lives in ADDRESS arithmetic only. 256 threads = 4 waves;
// wave w owns rows {2w,2w+1}; lane kc handles keys kc, kc+64. Double-buffered
// gload_lds; fp16 bias prefetched in registers. LDS carved from smem.
// ---------------------------------------------------------------------------
__device__ __forceinline__ void flash_body(
    char* smemraw, int qb, int bh,
    float* __restrict__ O, const float* __restrict__ Q,
    const __half* __restrict__ kT, const __half* __restrict__ vT,
    const __half* __restrict__ biasb, int NK)
{
  float4 (*Ks)[512] = (float4(*)[512])smemraw;            // 16KB
  float4 (*Vs)[512] = (float4(*)[512])(smemraw + 16384);  // 16KB
  float4* Qs = (float4*)(smemraw + 32768);                // 1KB
  const int b = bh >> 3, h = bh & 7;
  const int q0 = qb * 8;
  const int tid = threadIdx.x;
  const int w = tid >> 6, kc = tid & 63;
  const float4* Ktp = (const float4*)kT + (size_t)bh * NK * 4;
  const float4* Vtp = (const float4*)vT + (size_t)bh * NK * 4;
  if (tid < 64)
    Qs[tid] = ((const float4*)Q)[(size_t)(b * NQn + q0 + (tid >> 3)) * 64 +
                                 h * 8 + (tid & 7)];

  const __half* brow0 =
      biasb ? biasb + ((size_t)bh * NQn + q0 + 2 * w) * NK : nullptr;
  const __half* brow1 = biasb ? brow0 + NK : nullptr;

  auto stage = [&](int buf, int kb0) {
#pragma unroll
    for (int u = 0; u < 2; ++u) {
      const int s = tid + u * 256;   // linear LDS slot (lane order)
      const int k = s >> 2, e = s & 3;
      const int ok = (k + (k >> 2)) & 3;
      const int g = (kb0 + k) * 4 + ((e - ok) & 3);
      GLDS16(Ktp + g, &Ks[buf][s]);
      GLDS16(Vtp + g, &Vs[buf][s]);
    }
  };

  stage(0, 0);
  float cb[2][2];
  if (biasb) {
    cb[0][0] = __half2float(brow0[kc]);
    cb[0][1] = __half2float(brow0[kc + 64]);
    cb[1][0] = __half2float(brow1[kc]);
    cb[1][1] = __half2float(brow1[kc + 64]);
  }
  __syncthreads();  // drains vmcnt: chunk 0 + Qs ready

  float4 q[2][8];
#pragma unroll
  for (int dd = 0; dd < 8; ++dd) {
    q[0][dd] = Qs[(2 * w) * 8 + dd];
    q[1][dd] = Qs[(2 * w + 1) * 8 + dd];
  }
  float4 o[2][8] = {};
  float m_run[2] = {-3.0e38f, -3.0e38f};
  float l_run[2] = {0.f, 0.f};
  const int nchunk = NK >> 7;
  const int ox = (kc + (kc >> 2)) & 3;  // row-rot key, same for kc and kc+64

  for (int c = 0; c < nchunk; ++c) {
    const int cur = c & 1;
    float nb[2][2];
    if (c + 1 < nchunk) {
      stage(cur ^ 1, (c + 1) * 128);  // prefetch flies under compute
      if (biasb) {
        nb[0][0] = __half2float(brow0[(c + 1) * 128 + kc]);
        nb[0][1] = __half2float(brow0[(c + 1) * 128 + kc + 64]);
        nb[1][0] = __half2float(brow1[(c + 1) * 128 + kc]);
        nb[1][1] = __half2float(brow1[(c + 1) * 128 + kc + 64]);
      }
    }
    float s[2][2];
#pragma unroll
    for (int j = 0; j < 2; ++j) {
      const int kbase = (kc + j * 64) * 4;
      float a0 = 0.f, a1 = 0.f;
#pragma unroll
      for (int u = 0; u < 4; ++u) {
        float4 raw = Ks[cur][kbase + ((u + ox) & 3)];  // = unit u of row k
        const __half2* hp = (const __half2*)&raw;
        float2 f0 = __half22float2(hp[0]);
        float2 f1 = __half22float2(hp[1]);
        float2 f2 = __half22float2(hp[2]);
        float2 f3 = __half22float2(hp[3]);
        a0 += q[0][2 * u].x * f0.x + q[0][2 * u].y * f0.y +
              q[0][2 * u].z * f1.x + q[0][2 * u].w * f1.y +
              q[0][2 * u + 1].x * f2.x + q[0][2 * u + 1].y * f2.y +
              q[0][2 * u + 1].z * f3.x + q[0][2 * u + 1].w * f3.y;
        a1 += q[1][2 * u].x * f0.x + q[1][2 * u].y * f0.y +
              q[1][2 * u].z * f1.x + q[1][2 * u].w * f1.y +
              q[1][2 * u + 1].x * f2.x + q[1][2 * u + 1].y * f2.y +
              q[1][2 * u + 1].z * f3.x + q[1][2 * u + 1].w * f3.y;
      }
      s[0][j] = a0;
      s[1][j] = a1;
      if (biasb) { s[0][j] += cb[0][j]; s[1][j] += cb[1][j]; }
    }
    float f[2];
#pragma unroll
    for (int r = 0; r < 2; ++r) {
      float cmax = fmaxf(s[r][0], s[r][1]);
#pragma unroll
      for (int off = 1; off < 64; off <<= 1)
        cmax = fmaxf(cmax, __shfl_xor(cmax, off));
      const float m_new = fmaxf(m_run[r], cmax);
      f[r] = __expf(m_run[r] - m_new);
      s[r][0] = __expf(s[r][0] - m_new);
      s[r][1] = __expf(s[r][1] - m_new);
      float ls = s[r][0] + s[r][1];
#pragma unroll
      for (int off = 1; off < 64; off <<= 1) ls += __shfl_xor(ls, off);
      l_run[r] = l_run[r] * f[r] + ls;
      m_run[r] = m_new;
    }
#pragma unroll
    for (int dd = 0; dd < 8; ++dd) {
      o[0][dd].x *= f[0]; o[0][dd].y *= f[0]; o[0][dd].z *= f[0]; o[0][dd].w *= f[0];
      o[1][dd].x *= f[1]; o[1][dd].y *= f[1]; o[1][dd].z *= f[1]; o[1][dd].w *= f[1];
    }
#pragma unroll
    for (int j = 0; j < 2; ++j) {
      const int kbase = (kc + j * 64) * 4;
      const float p0 = s[0][j], p1 = s[1][j];
#pragma unroll
      for (int u = 0; u < 4; ++u) {
        float4 raw = Vs[cur][kbase + ((u + ox) & 3)];  // = unit u of row k
        const __half2* hp = (const __half2*)&raw;
        float2 f0 = __half22float2(hp[0]);
        float2 f1 = __half22float2(hp[1]);
        float2 f2 = __half22float2(hp[2]);
        float2 f3 = __half22float2(hp[3]);
        o[0][2 * u].x += p0 * f0.x; o[0][2 * u].y += p0 * f0.y;
        o[0][2 * u].z += p0 * f1.x; o[0][2 * u].w += p0 * f1.y;
        o[0][2 * u + 1].x += p0 * f2.x; o[0][2 * u + 1].y += p0 * f2.y;
        o[0][2 * u + 1].z += p0 * f3.x; o[0][2 * u + 1].w += p0 * f3.y;
        o[1][2 * u].x += p1 * f0.x; o[1][2 * u].y += p1 * f0.y;
        o[1][2 * u].z += p1 * f1.x; o[1][2 * u].w += p1 * f1.y;
        o[1][2 * u + 1].x += p1 * f2.x; o[1][2 * u + 1].y += p1 * f2.y;
        o[1][2 * u + 1].z += p1 * f3.x; o[1][2 * u + 1].w += p1 * f3.y;
      }
    }
    if (biasb && c + 1 < nchunk) {
      cb[0][0] = nb[0][0]; cb[0][1] = nb[0][1];
      cb[1][0] = nb[1][0]; cb[1][1] = nb[1][1];
    }
    __syncthreads();  // drains prefetch vmcnt + LDS reads before buffer reuse
  }
#pragma unroll
  for (int off = 1; off < 64; off <<= 1) {
#pragma unroll
    for (int dd = 0; dd < 8; ++dd) {
      o[0][dd].x += __shfl_xor(o[0][dd].x, off);
      o[0][dd].y += __shfl_xor(o[0][dd].y, off);
      o[0][dd].z += __shfl_xor(o[0][dd].z, off);
      o[0][dd].w += __shfl_xor(o[0][dd].w, off);
      o[1][dd].x += __shfl_xor(o[1][dd].x, off);
      o[1][dd].y += __shfl_xor(o[1][dd].y, off);
      o[1][dd].z += __shfl_xor(o[1][dd].z, off);
      o[1][dd].w += __shfl_xor(o[1][dd].w, off);
    }
  }
  if (kc == 0) {
    const float inv = 1.f / l_run[0];
#pragma unroll
    for (int dd = 0; dd < 8; ++dd) {
      float4 v = o[0][dd];
      v.x *= inv; v.y *= inv; v.z *= inv; v.w *= inv;
      ((float4*)O)[(size_t)(b * NQn + q0 + 2 * w) * 64 + h * 8 + dd] = v;
    }
  } else if (kc == 1) {
    const float inv = 1.f / l_run[1];
#pragma unroll
    for (int dd = 0; dd < 8; ++dd) {
      float4 v = o[1][dd];
      v.x *= inv; v.y *= inv; v.z *= inv; v.w *= inv;
      ((float4*)O)[(size_t)(b * NQn + q0 + 2 * w + 1) * 64 + h * 8 + dd] = v;
    }
  }
}

// ---------------------------------------------------------------------------
// fsb: fused flash-self (blocks 0..511) + bias materialization (512..1023).
// Independent work items; bias's memory-bound work overlaps flash's LDS-bound
// work instead of serializing as a separate dispatch.
// ---------------------------------------------------------------------------
__global__ __launch_bounds__(256, 2) void fsb_kernel(
    float* __restrict__ O, const float* __restrict__ Q,
    const __half* __restrict__ kT, const __half* __restrict__ vT,
    __half* __restrict__ biasb, const float* __restrict__ rel,
    const float* __restrict__ pad, const float* __restrict__ tsg,
    const float* __restrict__ Stabg, const float* __restrict__ Btabg)
{
  __shared__ __align__(16) char smem[34880];
  const int bx = blockIdx.x;
  if (bx < 512) {
    flash_body(smem, bx & 31, bx >> 5, O, Q, kT, vT, nullptr, NQn);
  } else {
    bias_body(smem, bx - 512, biasb, rel, pad, tsg, Stabg, Btabg);
  }
}

// ---------------------------------------------------------------------------
// flash standalone (cross): grid (NQ/8, B*H), 256 threads.
// ---------------------------------------------------------------------------
__global__ __launch_bounds__(256, 2) void flash_kernel(
    float* __restrict__ O, const float* __restrict__ Q,
    const __half* __restrict__ kT, const __half* __restrict__ vT,
    const __half* __restrict__ biasb, int NK)
{
  __shared__ __align__(16) char smem[33792];
  flash_body(smem, blockIdx.x, blockIdx.y, O, Q, kT, vT, biasb, NK);
}

// ---------------------------------------------------------------------------
// gemm64 standalone (FFN1): grid (N/64, M/64), 512 threads.
// ---------------------------------------------------------------------------
__global__ __launch_bounds__(512) void gemm64_kernel(
    float* __restrict__ C, const float* __restrict__ A,
    const float* __restrict__ W, const float* __restrict__ bias,
    int ld, int ldc, int do_relu)
{
  __shared__ float smem[4288];
  float (*As)[33] = (float(*)[33])smem;
  float (*WsT)[68] = (float(*)[68])(smem + 2112);
  gemm64_body(C, nullptr, ldc, A, nullptr, ld, W, bias, ld,
              blockIdx.y * 64, blockIdx.x * 64, blockIdx.x * 64, 1.f, do_relu,
              0, As, WsT);
}

// ---------------------------------------------------------------------------
// gemm32: 32x32 tile, 256 threads, 2x2/thread, K-step 32, float4 staging with
// register prefetch. Split-K via blockIdx.z (partials at kz*M*N).
// ---------------------------------------------------------------------------
__global__ __launch_bounds__(256) void gemm32_kernel(
    float* __restrict__ C, const float* __restrict__ A, const float* __restrict__ A2,
    const float* __restrict__ W, const float* __restrict__ bias,
    int N, int Kchunk, int Ktot, float scale)
{
  __shared__ float As[32][33];
  __shared__ float Ws[32][33];
  const int bm = blockIdx.y * 32, bn = blockIdx.x * 32;
  const int kz = blockIdx.z;
  const int M = gridDim.y * 32;
  float* Cp = C + (size_t)kz * M * N;
  const int tid = threadIdx.x;
  const int tx = tid & 15, ty = tid >> 4;
  const int lr = tid >> 3, lc = (tid & 7) * 4;
  float acc[2][2] = {};
  const int k00 = kz * Kchunk;
  float4 av, wv;
  {
    av = *(const float4*)(A + (size_t)(bm + lr) * Ktot + k00 + lc);
    if (A2) {
      float4 bv = *(const float4*)(A2 + (size_t)(bm + lr) * Ktot + k00 + lc);
      av.x += bv.x; av.y += bv.y; av.z += bv.z; av.w += bv.w;
    }
    wv = *(const float4*)(W + (size_t)(bn + lr) * Ktot + k00 + lc);
  }
  for (int k0 = k00; k0 < k00 + Kchunk; k0 += 32) {
    As[lr][lc] = av.x; As[lr][lc + 1] = av.y; As[lr][lc + 2] = av.z; As[lr][lc + 3] = av.w;
    Ws[lr][lc] = wv.x; Ws[lr][lc + 1] = wv.y; Ws[lr][lc + 2] = wv.z; Ws[lr][lc + 3] = wv.w;
    __syncthreads();
    if (k0 + 32 < k00 + Kchunk) {
      av = *(const float4*)(A + (size_t)(bm + lr) * Ktot + k0 + 32 + lc);
      if (A2) {
        float4 bv = *(const float4*)(A2 + (size_t)(bm + lr) * Ktot + k0 + 32 + lc);
        av.x += bv.x; av.y += bv.y; av.z += bv.z; av.w += bv.w;
      }
      wv = *(const float4*)(W + (size_t)(bn + lr) * Ktot + k0 + 32 + lc);
    }
#pragma unroll
    for (int k = 0; k < 32; ++k) {
      float a0 = As[ty * 2][k], a1 = As[ty * 2 + 1][k];
      float w0 = Ws[tx * 2][k], w1 = Ws[tx * 2 + 1][k];
      acc[0][0] += a0 * w0; acc[0][1] += a0 * w1;
      acc[1][0] += a1 * w0; acc[1][1] += a1 * w1;
    }
    __syncthreads();
  }
#pragma unroll
  for (int i = 0; i < 2; ++i) {
    int m = bm + ty * 2 + i;
#pragma unroll
    for (int j = 0; j < 2; ++j) {
      int n = bn + tx * 2 + j;
      float v = acc[i][j];
      if (bias) v += bias[n];
      Cp[(size_t)m * N + n] = v * scale;
    }
  }
}

// ---------------------------------------------------------------------------
// out = LayerNorm(resid + sum_{s<nsplit} part[s] + bias) * g + b.
// Generalized split-K reducer + residual + LN. grid: rows, block = 256 = D.
// ---------------------------------------------------------------------------
__global__ __launch_bounds__(256) void reduce_ln_kernel(
    float* __restrict__ out, const float* __restrict__ part,
    const float* __restrict__ bias, const float* __restrict__ resid,
    const float* __restrict__ g, const float* __restrict__ bt, int nsplit)
{
  const int row = blockIdx.x;
  const int t = threadIdx.x;
  const size_t idx = (size_t)row * Dn + t;
  const size_t STR = (size_t)Bb * NQn * Dn;
  float v = bias[t] + resid[idx];
  for (int s = 0; s < nsplit; ++s) v += part[idx + (size_t)s * STR];
  float sm = v, s2 = v * v;
#pragma unroll
  for (int off = 32; off > 0; off >>= 1) {
    sm += __shfl_down(sm, off);
    s2 += __shfl_down(s2, off);
  }
  __shared__ float rs[4], rs2[4], fin[2];
  const int lane = t & 63, wid = t >> 6;
  if (lane == 0) { rs[wid] = sm; rs2[wid] = s2; }
  __syncthreads();
  if (t == 0) {
    float a = rs[0] + rs[1] + rs[2] + rs[3];
    float a2 = rs2[0] + rs2[1] + rs2[2] + rs2[3];
    float mean = a * (1.f / Dn);
    float var = a2 * (1.f / Dn) - mean * mean;
    fin[0] = mean;
    fin[1] = rsqrtf(var + EPSf);
  }
  __syncthreads();
  out[idx] = (v - fin[0]) * fin[1] * g[t] + bt[t];
}

extern "C" void kernel_launch(void* const* d_in, const int* in_sizes, int n_in,
                              void* d_out, int out_size, void* d_ws, size_t ws_size,
                              hipStream_t stream)
{
  const float* tgt   = (const float*)d_in[0];
  const float* qpos  = (const float*)d_in[1];
  const float* src   = (const float*)d_in[2];
  const float* spe   = (const float*)d_in[3];
  const float* pad   = (const float*)d_in[4];
  const float* rel   = (const float*)d_in[5];
  const float* qw    = (const float*)d_in[6];
  const float* qb    = (const float*)d_in[7];
  const float* kw    = (const float*)d_in[8];
  const float* kb    = (const float*)d_in[9];
  const float* vw    = (const float*)d_in[10];
  const float* vb    = (const float*)d_in[11];
  const float* projw = (const float*)d_in[12];
  const float* projb = (const float*)d_in[13];
  const float* cpbw1 = (const float*)d_in[14];
  const float* cpbb1 = (const float*)d_in[15];
  const float* cpbw2 = (const float*)d_in[16];
  const float* ipw   = (const float*)d_in[17];
  const float* ipb   = (const float*)d_in[18];
  const float* outw  = (const float*)d_in[19];
  const float* outb  = (const float*)d_in[20];
  const float* ln1g  = (const float*)d_in[21];
  const float* ln1b  = (const float*)d_in[22];
  const float* ln2g  = (const float*)d_in[23];
  const float* ln2b  = (const float*)d_in[24];
  const float* ln3g  = (const float*)d_in[25];
  const float* ln3b  = (const float*)d_in[26];
  const float* ff1w  = (const float*)d_in[27];
  const float* ff1b  = (const float*)d_in[28];
  const float* ff2w  = (const float*)d_in[29];
  const float* ff2b  = (const float*)d_in[30];
  float* out = (float*)d_out;
  float* ws = (float*)d_ws;

  constexpr size_t SZ_Q   = (size_t)Bb * NQn * Dn;   // 131072
  constexpr size_t SZ_S   = (size_t)Bb * NSn * Dn;   // 524288
  constexpr size_t SZ_FFH = (size_t)Bb * NQn * FFNn; // 524288

  float* qSb  = ws;
  __half* kSb = (__half*)(qSb + SZ_Q);   // head-major fp16 kT (self)
  __half* vSb = (__half*)(qSb + 2 * SZ_Q);
  float* oSb  = ws + 3 * SZ_Q;
  float* soP  = oSb + SZ_Q;              // (unused; kept for layout stability)
  float* tgt2 = soP + SZ_Q;
  float* qCb  = tgt2 + SZ_Q;
  __half* kCb = (__half*)(qCb + SZ_Q);   // head-major fp16 kT (cross)
  __half* vCb = (__half*)(qCb + SZ_Q + SZ_S);
  float* oCb  = qCb + SZ_Q + 2 * SZ_S;
  float* coP  = oCb + SZ_Q;              // (unused)
  float* tgt3 = coP + SZ_Q;
  float* ffh  = tgt3 + SZ_Q;
  float* part = ffh + SZ_FFH;            // 4 * SZ_Q partials scratch
  float* tsb  = part + 4 * SZ_Q;
  float* Stab = tsb + RPEn;
  float* Btab = Stab + (RPEn + 1) * Hn;
  __half* biasb = (__half*)(Btab + (RPEn + 1) * Hn);

  const int MQ = Bb * NQn;  // 512

  // 1. prep: cpb tables + self QKV + cross KV (K/V transposed fp16 head-major)
  prep_kernel<<<dim3(96 + 256 + 1), dim3(512), 0, stream>>>(
      qSb, kSb, vSb, kCb, vCb, tgt, qpos, src, spe, ipw, ipb,
      kw, kb, vw, vb, cpbw1, cpbb1, cpbw2, tsb, Stab, Btab);

  // 2. fused: flash self (512 blocks) + fp16 bias materialization (512 blocks)
  fsb_kernel<<<dim3(1024), dim3(256), 0, stream>>>(
      oSb, qSb, kSb, vSb, biasb, rel, pad, tsb, Stab, Btab);

  // 3. self out-proj, split-K x2 -> partials (bias deferred to reducer)
  gemm32_kernel<<<dim3(Dn / 32, MQ / 32, 2), dim3(256), 0, stream>>>(
      part, oSb, nullptr, outw, nullptr, Dn, 128, Dn, 1.f);

  // 4. tgt2 = LN2(tgt + sum(part) + outb)
  reduce_ln_kernel<<<dim3(MQ), dim3(256), 0, stream>>>(
      tgt2, part, outb, tgt, ln2g, ln2b, 2);

  // 5. cross q
  gemm32_kernel<<<dim3(Dn / 32, MQ / 32, 1), dim3(256), 0, stream>>>(
      qCb, tgt2, qpos, qw, qb, Dn, Dn, Dn, SCALEf);

  // 6. cross attention (R=2 flash, fp16 K/V + fp16 staged bias)
  flash_kernel<<<dim3(NQn / 8, Bb * Hn), dim3(256), 0, stream>>>(
      oCb, qCb, kCb, vCb, biasb, NSn);

  // 7. cross out-proj, split-K x2 -> partials
  gemm32_kernel<<<dim3(Dn / 32, MQ / 32, 2), dim3(256), 0, stream>>>(
      part, oCb, nullptr, projw, nullptr, Dn, 128, Dn, 1.f);

  // 8. tgt3 = LN1(tgt2 + sum(part) + projb)
  reduce_ln_kernel<<<dim3(MQ), dim3(256), 0, stream>>>(
      tgt3, part, projb, tgt2, ln1g, ln1b, 2);

  // 9. FFN1 (relu)
  gemm64_kernel<<<dim3(FFNn / 64, MQ / 64), dim3(512), 0, stream>>>(
      ffh, tgt3, ff1w, ff1b, Dn, FFNn, 1);

  // 10. FFN2 split-K x4 -> partials
  gemm32_kernel<<<dim3(Dn / 32, MQ / 32, 4), dim3(256), 0, stream>>>(
      part, ffh, nullptr, ff2w, nullptr, Dn, 256, FFNn, 1.f);

  // 11. out = LN3(tgt3 + sum(part) + ff2b)
  reduce_ln_kernel<<<dim3(MQ), dim3(256), 0, stream>>>(
      out, part, ff2b, tgt3, ln3g, ln3b, 4);
}

// Round 16
// 125.583 us; speedup vs baseline: 1.2335x; 1.0279x over previous
//
#include <hip/hip_runtime.h>
#include <hip/hip_bf16.h>
#include <hip/hip_fp16.h>
#include <math.h>

#define Bb 2
#define NQn 256
#define NSn 1024
#define Dn 256
#define Hn 8
#define DHn 32
#define FFNn 1024
#define RPEn 512
#define SCALEf 0.17677669529663687f
#define EPSf 1e-5f

// async global->LDS, 16B per lane. LDS dest must be linear in lane order
// (wave-uniform base + lane*16); global src is per-lane (pre-swizzled).
#define GLDS16(g, l)                                                         \
  __builtin_amdgcn_global_load_lds(                                          \
      (const __attribute__((address_space(1))) void*)(const void*)(g),       \
      (__attribute__((address_space(3))) void*)(void*)(l), 16, 0, 0)

// ---------------------------------------------------------------------------
// gemm64 body: 64x64 tile, 512 threads, K-step 32, float4 loads, reg prefetch.
// trsh != 0: write transposed head-major FP16 Ch[((b*H+h)<<trsh)+kseq][32].
// ---------------------------------------------------------------------------
__device__ __forceinline__ void gemm64_body(
    float* __restrict__ C, __half* __restrict__ Ch, int ldc,
    const float* __restrict__ A, const float* __restrict__ A2, int ld,
    const float* __restrict__ W, const float* __restrict__ bias,
    int K, int bm, int bnC, int bnW, float scale, int do_relu, int trsh,
    float (*As)[33], float (*WsT)[68])
{
  const int tid = threadIdx.x;
  const int tx = tid & 15, ty = tid >> 4;       // ty 0..31
  const int lr = tid >> 3, lc = (tid & 7) * 4;  // staging coords
  float4 ra, rw;
  {
    ra = *(const float4*)(A + (size_t)(bm + lr) * ld + lc);
    if (A2) {
      float4 t = *(const float4*)(A2 + (size_t)(bm + lr) * ld + lc);
      ra.x += t.x; ra.y += t.y; ra.z += t.z; ra.w += t.w;
    }
    rw = *(const float4*)(W + (size_t)(bnW + lr) * ld + lc);
  }
  float acc[2][4] = {};
  for (int k0 = 0; k0 < K; k0 += 32) {
    As[lr][lc] = ra.x; As[lr][lc + 1] = ra.y;
    As[lr][lc + 2] = ra.z; As[lr][lc + 3] = ra.w;
    WsT[lc][lr] = rw.x; WsT[lc + 1][lr] = rw.y;
    WsT[lc + 2][lr] = rw.z; WsT[lc + 3][lr] = rw.w;
    __syncthreads();
    if (k0 + 32 < K) {
      ra = *(const float4*)(A + (size_t)(bm + lr) * ld + k0 + 32 + lc);
      if (A2) {
        float4 t = *(const float4*)(A2 + (size_t)(bm + lr) * ld + k0 + 32 + lc);
        ra.x += t.x; ra.y += t.y; ra.z += t.z; ra.w += t.w;
      }
      rw = *(const float4*)(W + (size_t)(bnW + lr) * ld + k0 + 32 + lc);
    }
#pragma unroll
    for (int k = 0; k < 32; ++k) {
      float a0 = As[ty][k], a1 = As[ty + 32][k];
      float4 w = *(const float4*)&WsT[k][tx * 4];
      acc[0][0] += a0 * w.x; acc[0][1] += a0 * w.y;
      acc[0][2] += a0 * w.z; acc[0][3] += a0 * w.w;
      acc[1][0] += a1 * w.x; acc[1][1] += a1 * w.y;
      acc[1][2] += a1 * w.z; acc[1][3] += a1 * w.w;
    }
    __syncthreads();
  }
#pragma unroll
  for (int i = 0; i < 2; ++i) {
    int m = bm + ty + i * 32;
#pragma unroll
    for (int j = 0; j < 4; ++j) {
      float v = acc[i][j];
      if (bias) v += bias[bnW + tx * 4 + j];
      v *= scale;
      if (do_relu) v = fmaxf(v, 0.f);
      if (trsh == 0) {
        C[(size_t)m * ldc + bnC + tx * 4 + j] = v;
      } else {
        const int nC = bnC + tx * 4 + j;
        const int bb = m >> trsh, kseq = m & ((1 << trsh) - 1);
        const int hh = nC >> 5, d = nC & 31;
        Ch[((((size_t)(bb * Hn + hh)) << trsh) + kseq) * 32 + d] =
            __float2half(v);
      }
    }
  }
}

// ---------------------------------------------------------------------------
// prep: fused build_cpb (1 block) + self QKV GEMM (96 blocks; K/V written
// head-major transposed fp16) + cross KV GEMM (256 blocks). 512 threads.
// ---------------------------------------------------------------------------
__global__ __launch_bounds__(512) void prep_kernel(
    float* __restrict__ qSb, __half* __restrict__ kSb, __half* __restrict__ vSb,
    __half* __restrict__ kCb, __half* __restrict__ vCb,
    const float* __restrict__ tgt, const float* __restrict__ qpos,
    const float* __restrict__ src, const float* __restrict__ spe,
    const float* __restrict__ ipw, const float* __restrict__ ipb,
    const float* __restrict__ kw, const float* __restrict__ kb,
    const float* __restrict__ vw, const float* __restrict__ vb,
    const float* __restrict__ w1p, const float* __restrict__ b1p,
    const float* __restrict__ w2p,
    float* __restrict__ tout, float* __restrict__ Stab, float* __restrict__ Btab)
{
  __shared__ float smem[4288];  // As 64*33=2112 + WsT 32*68=2176
  const int bx = blockIdx.x;
  const int tid = threadIdx.x;
  if (bx < 96) {
    float (*As)[33] = (float(*)[33])smem;
    float (*WsT)[68] = (float(*)[68])(smem + 2112);
    int my = bx & 7, nx = bx >> 3;
    int sec = nx >> 2;
    gemm64_body(qSb, sec == 1 ? kSb : vSb, Dn, tgt,
                sec < 2 ? qpos : nullptr, Dn, ipw, ipb,
                Dn, my * 64, (nx & 3) * 64, nx * 64,
                sec == 0 ? SCALEf : 1.f, 0, sec == 0 ? 0 : 8, As, WsT);
    return;
  }
  if (bx < 96 + 256) {
    float (*As)[33] = (float(*)[33])smem;
    float (*WsT)[68] = (float(*)[68])(smem + 2112);
    int idx = bx - 96;
    int my = idx & 31, nx = idx >> 5;
    int sec = nx >> 2;
    gemm64_body(nullptr, sec ? vCb : kCb, Dn, src, sec ? nullptr : spe, Dn,
                sec ? vw : kw, sec ? vb : kb,
                Dn, my * 64, (nx & 3) * 64, (nx & 3) * 64, 1.f, 0, 10, As, WsT);
    return;
  }
  // ---- cpb piecewise-linear table build (verified rounds 1-15) ----
  float* key = smem;
  int* pidx = (int*)(smem + 512);
  float* w1s = smem + 1024;
  float* b1s = smem + 1536;
  {
    float w = w1p[tid], bb = b1p[tid];
    key[tid] = (w != 0.f) ? (-bb / w) : 3.0e38f;
    pidx[tid] = tid;
  }
  __syncthreads();
  for (int k = 2; k <= RPEn; k <<= 1) {
    for (int j = k >> 1; j > 0; j >>= 1) {
      int ixj = tid ^ j;
      if (ixj > tid) {
        float a = key[tid], c = key[ixj];
        bool asc = ((tid & k) == 0);
        bool sw = asc ? (a > c) : (a < c);
        if (sw) {
          key[tid] = c; key[ixj] = a;
          int tmp = pidx[tid]; pidx[tid] = pidx[ixj]; pidx[ixj] = tmp;
        }
      }
      __syncthreads();
    }
  }
  w1s[tid] = w1p[pidx[tid]];
  b1s[tid] = b1p[pidx[tid]];
  tout[tid] = key[tid];
  __syncthreads();
  const int lane = tid & 63;
  const int h = tid >> 6;
  const int j0 = lane * 8;
  float sp[8], bp[8], sn[8], bn[8];
  float csp = 0.f, cbp = 0.f, csn = 0.f, cbn = 0.f, ccc = 0.f;
#pragma unroll
  for (int e = 0; e < 8; ++e) {
    int j = j0 + e;
    float w = w1s[j], b = b1s[j];
    float c = w2p[h * RPEn + pidx[j]];
    sp[e] = csp; bp[e] = cbp; sn[e] = csn; bn[e] = cbn;
    if (w > 0.f)      { csp += w * c; cbp += b * c; }
    else if (w < 0.f) { csn += w * c; cbn += b * c; }
    else              { ccc += fmaxf(b, 0.f) * c; }
  }
  float isp = csp, ibp = cbp, isn = csn, ibn = cbn, icc = ccc;
#pragma unroll
  for (int d = 1; d < 64; d <<= 1) {
    float t0 = __shfl_up(isp, d);
    float t1 = __shfl_up(ibp, d);
    float t2 = __shfl_up(isn, d);
    float t3 = __shfl_up(ibn, d);
    if (lane >= d) { isp += t0; ibp += t1; isn += t2; ibn += t3; }
    icc += __shfl_xor(icc, d);
  }
  const float tsn = __shfl(isn, 63);
  const float tbn = __shfl(ibn, 63);
  const float esp = isp - csp, ebp = ibp - cbp;
  const float esn = isn - csn, ebn = ibn - cbn;
#pragma unroll
  for (int e = 0; e < 8; ++e) {
    int j = j0 + e;
    Stab[j * Hn + h] = (esp + sp[e]) + (tsn - (esn + sn[e]));
    Btab[j * Hn + h] = (ebp + bp[e]) + (tbn - (ebn + bn[e])) + icc;
  }
  if (lane == 63) {
    Stab[RPEn * Hn + h] = isp;
    Btab[RPEn * Hn + h] = ibp + icc;
  }
}

// ---------------------------------------------------------------------------
// bias body: fp16 bias[b,h,q,k] = Sh[lo]*m + Bh[lo] - 100*pad. One block per
// (b,q); search once per (b,q,k), applied to 8 heads. LDS carved from smem.
// ---------------------------------------------------------------------------
__device__ __forceinline__ void bias_body(
    char* smemraw, int idx,
    __half* __restrict__ biasb, const float* __restrict__ rel,
    const float* __restrict__ pad, const float* __restrict__ tsg,
    const float* __restrict__ Stabg, const float* __restrict__ Btabg)
{
  float* ts = (float*)smemraw;                    // 512 f
  float* Sh = (float*)(smemraw + 2048);           // 4104 f
  float* Bh = (float*)(smemraw + 18464);          // 4104 f
  const int tid = threadIdx.x;
  const int b = idx >> 8, q = idx & 255;
  ts[tid] = tsg[tid];
  ts[tid + 256] = tsg[tid + 256];
  for (int i = tid; i < (RPEn + 1) * Hn; i += 256) {
    Sh[i] = Stabg[i];
    Bh[i] = Btabg[i];
  }
  __syncthreads();
#pragma unroll
  for (int j = 0; j < 4; ++j) {
    const int k = tid + j * 256;
    const float m = rel[((size_t)b * NQn + q) * NSn + k];
    const float padv = -100.f * pad[b * NSn + k];
    int lo = 0, hi = RPEn;
#pragma unroll
    for (int it = 0; it < 9; ++it) {
      int mid = (lo + hi) >> 1;
      if (ts[mid] < m) lo = mid + 1; else hi = mid;
    }
#pragma unroll
    for (int h = 0; h < Hn; ++h) {
      biasb[(((size_t)(b * Hn + h)) * NQn + q) * NSn + k] =
          __float2half(Sh[lo * Hn + h] * m + Bh[lo * Hn + h] + padv);
    }
  }
}

// ---------------------------------------------------------------------------
// Flash body (verified rounds 14-15), templated on CHUNK (keys per LDS tile).
// R=2 rows/thread, HEAD-MAJOR FP16 K/V (kT/vT [b][h][k][32], rows = 64B =
// 4 float4 units). Rotation swizzle o(k)=(k+(k>>2))&3 in ADDRESS arithmetic
// only ((kc + j*64) preserves it: 80j = 0 mod 4). 256 threads = 4 waves;
// wave w owns rows {2w,2w+1}; lane kc handles keys kc + j*64, j<CHUNK/64.
// Double-buffered gload_lds; fp16 bias prefetched in registers.
// LDS: 2*CHUNK*64*2 + 1KB (=33.8KB @128, 66.5KB @256 -> 2 blocks/CU).
// ---------------------------------------------------------------------------
template <int CHUNK>
__device__ __forceinline__ void flash_body(
    char* smemraw, int qb, int bh,
    float* __restrict__ O, const float* __restrict__ Q,
    const __half* __restrict__ kT, const __half* __restrict__ vT,
    const __half* __restrict__ biasb, int NK)
{
  constexpr int NJ = CHUNK / 64;        // keys per lane per chunk
  constexpr int NS = CHUNK / 64;        // stage iters (CHUNK*4 slots/256 thr)
  float4 (*Ks)[CHUNK * 4] = (float4(*)[CHUNK * 4])smemraw;
  float4 (*Vs)[CHUNK * 4] = (float4(*)[CHUNK * 4])(smemraw + CHUNK * 128);
  float4* Qs = (float4*)(smemraw + CHUNK * 256);
  const int b = bh >> 3, h = bh & 7;
  const int q0 = qb * 8;
  const int tid = threadIdx.x;
  const int w = tid >> 6, kc = tid & 63;
  const float4* Ktp = (const float4*)kT + (size_t)bh * NK * 4;
  const float4* Vtp = (const float4*)vT + (size_t)bh * NK * 4;
  if (tid < 64)
    Qs[tid] = ((const float4*)Q)[(size_t)(b * NQn + q0 + (tid >> 3)) * 64 +
                                 h * 8 + (tid & 7)];

  const __half* brow0 =
      biasb ? biasb + ((size_t)bh * NQn + q0 + 2 * w) * NK : nullptr;
  const __half* brow1 = biasb ? brow0 + NK : nullptr;

  auto stage = [&](int buf, int kb0) {
#pragma unroll
    for (int u = 0; u < NS; ++u) {
      const int s = tid + u * 256;   // linear LDS slot (lane order)
      const int k = s >> 2, e = s & 3;
      const int ok = (k + (k >> 2)) & 3;
      const int g = (kb0 + k) * 4 + ((e - ok) & 3);
      GLDS16(Ktp + g, &Ks[buf][s]);
      GLDS16(Vtp + g, &Vs[buf][s]);
    }
  };

  stage(0, 0);
  float cb[2][NJ];
  if (biasb) {
#pragma unroll
    for (int j = 0; j < NJ; ++j) {
      cb[0][j] = __half2float(brow0[kc + j * 64]);
      cb[1][j] = __half2float(brow1[kc + j * 64]);
    }
  }
  __syncthreads();  // drains vmcnt: chunk 0 + Qs ready

  float4 q[2][8];
#pragma unroll
  for (int dd = 0; dd < 8; ++dd) {
    q[0][dd] = Qs[(2 * w) * 8 + dd];
    q[1][dd] = Qs[(2 * w + 1) * 8 + dd];
  }
  float4 o[2][8] = {};
  float m_run[2] = {-3.0e38f, -3.0e38f};
  float l_run[2] = {0.f, 0.f};
  const int nchunk = NK / CHUNK;
  const int ox = (kc + (kc >> 2)) & 3;  // row-rot key, invariant to j*64

  for (int c = 0; c < nchunk; ++c) {
    const int cur = c & 1;
    float nb[2][NJ];
    if (c + 1 < nchunk) {
      stage(cur ^ 1, (c + 1) * CHUNK);  // prefetch flies under compute
      if (biasb) {
#pragma unroll
        for (int j = 0; j < NJ; ++j) {
          nb[0][j] = __half2float(brow0[(c + 1) * CHUNK + kc + j * 64]);
          nb[1][j] = __half2float(brow1[(c + 1) * CHUNK + kc + j * 64]);
        }
      }
    }
    float s[2][NJ];
#pragma unroll
    for (int j = 0; j < NJ; ++j) {
      const int kbase = (kc + j * 64) * 4;
      float a0 = 0.f, a1 = 0.f;
#pragma unroll
      for (int u = 0; u < 4; ++u) {
        float4 raw = Ks[cur][kbase + ((u + ox) & 3)];  // = unit u of row k
        const __half2* hp = (const __half2*)&raw;
        float2 f0 = __half22float2(hp[0]);
        float2 f1 = __half22float2(hp[1]);
        float2 f2 = __half22float2(hp[2]);
        float2 f3 = __half22float2(hp[3]);
        a0 += q[0][2 * u].x * f0.x + q[0][2 * u].y * f0.y +
              q[0][2 * u].z * f1.x + q[0][2 * u].w * f1.y +
              q[0][2 * u + 1].x * f2.x + q[0][2 * u + 1].y * f2.y +
              q[0][2 * u + 1].z * f3.x + q[0][2 * u + 1].w * f3.y;
        a1 += q[1][2 * u].x * f0.x + q[1][2 * u].y * f0.y +
              q[1][2 * u].z * f1.x + q[1][2 * u].w * f1.y +
              q[1][2 * u + 1].x * f2.x + q[1][2 * u + 1].y * f2.y +
              q[1][2 * u + 1].z * f3.x + q[1][2 * u + 1].w * f3.y;
      }
      s[0][j] = a0;
      s[1][j] = a1;
      if (biasb) { s[0][j] += cb[0][j]; s[1][j] += cb[1][j]; }
    }
    float f[2];
#pragma unroll
    for (int r = 0; r < 2; ++r) {
      float cmax = s[r][0];
#pragma unroll
      for (int j = 1; j < NJ; ++j) cmax = fmaxf(cmax, s[r][j]);
#pragma unroll
      for (int off = 1; off < 64; off <<= 1)
        cmax = fmaxf(cmax, __shfl_xor(cmax, off));
      const float m_new = fmaxf(m_run[r], cmax);
      f[r] = __expf(m_run[r] - m_new);
      float ls = 0.f;
#pragma unroll
      for (int j = 0; j < NJ; ++j) {
        s[r][j] = __expf(s[r][j] - m_new);
        ls += s[r][j];
      }
#pragma unroll
      for (int off = 1; off < 64; off <<= 1) ls += __shfl_xor(ls, off);
      l_run[r] = l_run[r] * f[r] + ls;
      m_run[r] = m_new;
    }
#pragma unroll
    for (int dd = 0; dd < 8; ++dd) {
      o[0][dd].x *= f[0]; o[0][dd].y *= f[0]; o[0][dd].z *= f[0]; o[0][dd].w *= f[0];
      o[1][dd].x *= f[1]; o[1][dd].y *= f[1]; o[1][dd].z *= f[1]; o[1][dd].w *= f[1];
    }
#pragma unroll
    for (int j = 0; j < NJ; ++j) {
      const int kbase = (kc + j * 64) * 4;
      const float p0 = s[0][j], p1 = s[1][j];
#pragma unroll
      for (int u = 0; u < 4; ++u) {
        float4 raw = Vs[cur][kbase + ((u + ox) & 3)];  // = unit u of row k
        const __half2* hp = (const __half2*)&raw;
        float2 f0 = __half22float2(hp[0]);
        float2 f1 = __half22float2(hp[1]);
        float2 f2 = __half22float2(hp[2]);
        float2 f3 = __half22float2(hp[3]);
        o[0][2 * u].x += p0 * f0.x; o[0][2 * u].y += p0 * f0.y;
        o[0][2 * u].z += p0 * f1.x; o[0][2 * u].w += p0 * f1.y;
        o[0][2 * u + 1].x += p0 * f2.x; o[0][2 * u + 1].y += p0 * f2.y;
        o[0][2 * u + 1].z += p0 * f3.x; o[0][2 * u + 1].w += p0 * f3.y;
        o[1][2 * u].x += p1 * f0.x; o[1][2 * u].y += p1 * f0.y;
        o[1][2 * u].z += p1 * f1.x; o[1][2 * u].w += p1 * f1.y;
        o[1][2 * u + 1].x += p1 * f2.x; o[1][2 * u + 1].y += p1 * f2.y;
        o[1][2 * u + 1].z += p1 * f3.x; o[1][2 * u + 1].w += p1 * f3.y;
      }
    }
    if (biasb && c + 1 < nchunk) {
#pragma unroll
      for (int j = 0; j < NJ; ++j) {
        cb[0][j] = nb[0][j];
        cb[1][j] = nb[1][j];
      }
    }
    __syncthreads();  // drains prefetch vmcnt + LDS reads before buffer reuse
  }
#pragma unroll
  for (int off = 1; off < 64; off <<= 1) {
#pragma unroll
    for (int dd = 0; dd < 8; ++dd) {
      o[0][dd].x += __shfl_xor(o[0][dd].x, off);
      o[0][dd].y += __shfl_xor(o[0][dd].y, off);
      o[0][dd].z += __shfl_xor(o[0][dd].z, off);
      o[0][dd].w += __shfl_xor(o[0][dd].w, off);
      o[1][dd].x += __shfl_xor(o[1][dd].x, off);
      o[1][dd].y += __shfl_xor(o[1][dd].y, off);
      o[1][dd].z += __shfl_xor(o[1][dd].z, off);
      o[1][dd].w += __shfl_xor(o[1][dd].w, off);
    }
  }
  if (kc == 0) {
    const float inv = 1.f / l_run[0];
#pragma unroll
    for (int dd = 0; dd < 8; ++dd) {
      float4 v = o[0][dd];
      v.x *= inv; v.y *= inv; v.z *= inv; v.w *= inv;
      ((float4*)O)[(size_t)(b * NQn + q0 + 2 * w) * 64 + h * 8 + dd] = v;
    }
  } else if (kc == 1) {
    const float inv = 1.f / l_run[1];
#pragma unroll
    for (int dd = 0; dd < 8; ++dd) {
      float4 v = o[1][dd];
      v.x *= inv; v.y *= inv; v.z *= inv; v.w *= inv;
      ((float4*)O)[(size_t)(b * NQn + q0 + 2 * w + 1) * 64 + h * 8 + dd] = v;
    }
  }
}

// ---------------------------------------------------------------------------
// fsb: fused flash-self (blocks 0..511, CHUNK=128) + bias materialization
// (512..1023). Independent work; bias's memory-bound work overlaps flash.
// ---------------------------------------------------------------------------
__global__ __launch_bounds__(256, 2) void fsb_kernel(
    float* __restrict__ O, const float* __restrict__ Q,
    const __half* __restrict__ kT, const __half* __restrict__ vT,
    __half* __restrict__ biasb, const float* __restrict__ rel,
    const float* __restrict__ pad, const float* __restrict__ tsg,
    const float* __restrict__ Stabg, const float* __restrict__ Btabg)
{
  __shared__ __align__(16) char smem[34880];
  const int bx = blockIdx.x;
  if (bx < 512) {
    flash_body<128>(smem, bx & 31, bx >> 5, O, Q, kT, vT, nullptr, NQn);
  } else {
    bias_body(smem, bx - 512, biasb, rel, pad, tsg, Stabg, Btabg);
  }
}

// ---------------------------------------------------------------------------
// flash standalone (cross, CHUNK=256): grid (NQ/8, B*H), 256 threads.
// 66.5 KB LDS -> 2 blocks/CU, 512 blocks in one round; 4 chunks of 256 keys
// amortize per-chunk barrier + softmax-chain overhead 2x vs CHUNK=128.
// ---------------------------------------------------------------------------
__global__ __launch_bounds__(256, 2) void flash_kernel(
    float* __restrict__ O, const float* __restrict__ Q,
    const __half* __restrict__ kT, const __half* __restrict__ vT,
    const __half* __restrict__ biasb, int NK)
{
  __shared__ __align__(16) char smem[66560];
  flash_body<256>(smem, blockIdx.x, blockIdx.y, O, Q, kT, vT, biasb, NK);
}

// ---------------------------------------------------------------------------
// gemm32: 32x32 tile, 256 threads, 2x2/thread, K-step 32, float4 staging with
// register prefetch. Split-K via blockIdx.z (partials at kz*M*N). relu opt.
// ---------------------------------------------------------------------------
__global__ __launch_bounds__(256) void gemm32_kernel(
    float* __restrict__ C, const float* __restrict__ A, const float* __restrict__ A2,
    const float* __restrict__ W, const float* __restrict__ bias,
    int N, int Kchunk, int Ktot, float scale, int do_relu)
{
  __shared__ float As[32][33];
  __shared__ float Ws[32][33];
  const int bm = blockIdx.y * 32, bn = blockIdx.x * 32;
  const int kz = blockIdx.z;
  const int M = gridDim.y * 32;
  float* Cp = C + (size_t)kz * M * N;
  const int tid = threadIdx.x;
  const int tx = tid & 15, ty = tid >> 4;
  const int lr = tid >> 3, lc = (tid & 7) * 4;
  float acc[2][2] = {};
  const int k00 = kz * Kchunk;
  float4 av, wv;
  {
    av = *(const float4*)(A + (size_t)(bm + lr) * Ktot + k00 + lc);
    if (A2) {
      float4 bv = *(const float4*)(A2 + (size_t)(bm + lr) * Ktot + k00 + lc);
      av.x += bv.x; av.y += bv.y; av.z += bv.z; av.w += bv.w;
    }
    wv = *(const float4*)(W + (size_t)(bn + lr) * Ktot + k00 + lc);
  }
  for (int k0 = k00; k0 < k00 + Kchunk; k0 += 32) {
    As[lr][lc] = av.x; As[lr][lc + 1] = av.y; As[lr][lc + 2] = av.z; As[lr][lc + 3] = av.w;
    Ws[lr][lc] = wv.x; Ws[lr][lc + 1] = wv.y; Ws[lr][lc + 2] = wv.z; Ws[lr][lc + 3] = wv.w;
    __syncthreads();
    if (k0 + 32 < k00 + Kchunk) {
      av = *(const float4*)(A + (size_t)(bm + lr) * Ktot + k0 + 32 + lc);
      if (A2) {
        float4 bv = *(const float4*)(A2 + (size_t)(bm + lr) * Ktot + k0 + 32 + lc);
        av.x += bv.x; av.y += bv.y; av.z += bv.z; av.w += bv.w;
      }
      wv = *(const float4*)(W + (size_t)(bn + lr) * Ktot + k0 + 32 + lc);
    }
#pragma unroll
    for (int k = 0; k < 32; ++k) {
      float a0 = As[ty * 2][k], a1 = As[ty * 2 + 1][k];
      float w0 = Ws[tx * 2][k], w1 = Ws[tx * 2 + 1][k];
      acc[0][0] += a0 * w0; acc[0][1] += a0 * w1;
      acc[1][0] += a1 * w0; acc[1][1] += a1 * w1;
    }
    __syncthreads();
  }
#pragma unroll
  for (int i = 0; i < 2; ++i) {
    int m = bm + ty * 2 + i;
#pragma unroll
    for (int j = 0; j < 2; ++j) {
      int n = bn + tx * 2 + j;
      float v = acc[i][j];
      if (bias) v += bias[n];
      v *= scale;
      if (do_relu) v = fmaxf(v, 0.f);
      Cp[(size_t)m * N + n] = v;
    }
  }
}

// ---------------------------------------------------------------------------
// out = LayerNorm(resid + sum_{s<nsplit} part[s] + bias) * g + b.
// Generalized split-K reducer + residual + LN. grid: rows, block = 256 = D.
// ---------------------------------------------------------------------------
__global__ __launch_bounds__(256) void reduce_ln_kernel(
    float* __restrict__ out, const float* __restrict__ part,
    const float* __restrict__ bias, const float* __restrict__ resid,
    const float* __restrict__ g, const float* __restrict__ bt, int nsplit)
{
  const int row = blockIdx.x;
  const int t = threadIdx.x;
  const size_t idx = (size_t)row * Dn + t;
  const size_t STR = (size_t)Bb * NQn * Dn;
  float v = bias[t] + resid[idx];
  for (int s = 0; s < nsplit; ++s) v += part[idx + (size_t)s * STR];
  float sm = v, s2 = v * v;
#pragma unroll
  for (int off = 32; off > 0; off >>= 1) {
    sm += __shfl_down(sm, off);
    s2 += __shfl_down(s2, off);
  }
  __shared__ float rs[4], rs2[4], fin[2];
  const int lane = t & 63, wid = t >> 6;
  if (lane == 0) { rs[wid] = sm; rs2[wid] = s2; }
  __syncthreads();
  if (t == 0) {
    float a = rs[0] + rs[1] + rs[2] + rs[3];
    float a2 = rs2[0] + rs2[1] + rs2[2] + rs2[3];
    float mean = a * (1.f / Dn);
    float var = a2 * (1.f / Dn) - mean * mean;
    fin[0] = mean;
    fin[1] = rsqrtf(var + EPSf);
  }
  __syncthreads();
  out[idx] = (v - fin[0]) * fin[1] * g[t] + bt[t];
}

extern "C" void kernel_launch(void* const* d_in, const int* in_sizes, int n_in,
                              void* d_out, int out_size, void* d_ws, size_t ws_size,
                              hipStream_t stream)
{
  const float* tgt   = (const float*)d_in[0];
  const float* qpos  = (const float*)d_in[1];
  const float* src   = (const float*)d_in[2];
  const float* spe   = (const float*)d_in[3];
  const float* pad   = (const float*)d_in[4];
  const float* rel   = (const float*)d_in[5];
  const float* qw    = (const float*)d_in[6];
  const float* qb    = (const float*)d_in[7];
  const float* kw    = (const float*)d_in[8];
  const float* kb    = (const float*)d_in[9];
  const float* vw    = (const float*)d_in[10];
  const float* vb    = (const float*)d_in[11];
  const float* projw = (const float*)d_in[12];
  const float* projb = (const float*)d_in[13];
  const float* cpbw1 = (const float*)d_in[14];
  const float* cpbb1 = (const float*)d_in[15];
  const float* cpbw2 = (const float*)d_in[16];
  const float* ipw   = (const float*)d_in[17];
  const float* ipb   = (const float*)d_in[18];
  const float* outw  = (const float*)d_in[19];
  const float* outb  = (const float*)d_in[20];
  const float* ln1g  = (const float*)d_in[21];
  const float* ln1b  = (const float*)d_in[22];
  const float* ln2g  = (const float*)d_in[23];
  const float* ln2b  = (const float*)d_in[24];
  const float* ln3g  = (const float*)d_in[25];
  const float* ln3b  = (const float*)d_in[26];
  const float* ff1w  = (const float*)d_in[27];
  const float* ff1b  = (const float*)d_in[28];
  const float* ff2w  = (const float*)d_in[29];
  const float* ff2b  = (const float*)d_in[30];
  float* out = (float*)d_out;
  float* ws = (float*)d_ws;

  constexpr size_t SZ_Q   = (size_t)Bb * NQn * Dn;   // 131072
  constexpr size_t SZ_S   = (size_t)Bb * NSn * Dn;   // 524288
  constexpr size_t SZ_FFH = (size_t)Bb * NQn * FFNn; // 524288

  float* qSb  = ws;
  __half* kSb = (__half*)(qSb + SZ_Q);   // head-major fp16 kT (self)
  __half* vSb = (__half*)(qSb + 2 * SZ_Q);
  float* oSb  = ws + 3 * SZ_Q;
  float* soP  = oSb + SZ_Q;              // (layout stability)
  float* tgt2 = soP + SZ_Q;
  float* qCb  = tgt2 + SZ_Q;
  __half* kCb = (__half*)(qCb + SZ_Q);   // head-major fp16 kT (cross)
  __half* vCb = (__half*)(qCb + SZ_Q + SZ_S);
  float* oCb  = qCb + SZ_Q + 2 * SZ_S;
  float* coP  = oCb + SZ_Q;              // (layout stability)
  float* tgt3 = coP + SZ_Q;
  float* ffh  = tgt3 + SZ_Q;
  float* part = ffh + SZ_FFH;            // 4 * SZ_Q partials scratch
  float* tsb  = part + 4 * SZ_Q;
  float* Stab = tsb + RPEn;
  float* Btab = Stab + (RPEn + 1) * Hn;
  __half* biasb = (__half*)(Btab + (RPEn + 1) * Hn);

  const int MQ = Bb * NQn;  // 512

  // 1. prep: cpb tables + self QKV + cross KV (K/V transposed fp16 head-major)
  prep_kernel<<<dim3(96 + 256 + 1), dim3(512), 0, stream>>>(
      qSb, kSb, vSb, kCb, vCb, tgt, qpos, src, spe, ipw, ipb,
      kw, kb, vw, vb, cpbw1, cpbb1, cpbw2, tsb, Stab, Btab);

  // 2. fused: flash self (512 blocks) + fp16 bias materialization (512 blocks)
  fsb_kernel<<<dim3(1024), dim3(256), 0, stream>>>(
      oSb, qSb, kSb, vSb, biasb, rel, pad, tsb, Stab, Btab);

  // 3. self out-proj, split-K x2 -> partials (bias deferred to reducer)
  gemm32_kernel<<<dim3(Dn / 32, MQ / 32, 2), dim3(256), 0, stream>>>(
      part, oSb, nullptr, outw, nullptr, Dn, 128, Dn, 1.f, 0);

  // 4. tgt2 = LN2(tgt + sum(part) + outb)
  reduce_ln_kernel<<<dim3(MQ), dim3(256), 0, stream>>>(
      tgt2, part, outb, tgt, ln2g, ln2b, 2);

  // 5. cross q
  gemm32_kernel<<<dim3(Dn / 32, MQ / 32, 1), dim3(256), 0, stream>>>(
      qCb, tgt2, qpos, qw, qb, Dn, Dn, Dn, SCALEf, 0);

  // 6. cross attention (CHUNK=256 flash, fp16 K/V + fp16 staged bias)
  flash_kernel<<<dim3(NQn / 8, Bb * Hn), dim3(256), 0, stream>>>(
      oCb, qCb, kCb, vCb, biasb, NSn);

  // 7. cross out-proj, split-K x2 -> partials
  gemm32_kernel<<<dim3(Dn / 32, MQ / 32, 2), dim3(256), 0, stream>>>(
      part, oCb, nullptr, projw, nullptr, Dn, 128, Dn, 1.f, 0);

  // 8. tgt3 = LN1(tgt2 + sum(part) + projb)
  reduce_ln_kernel<<<dim3(MQ), dim3(256), 0, stream>>>(
      tgt3, part, projb, tgt2, ln1g, ln1b, 2);

  // 9. FFN1 (relu) as gemm32: 512 blocks (full GPU) instead of gemm64's 128
  gemm32_kernel<<<dim3(FFNn / 32, MQ / 32, 1), dim3(256), 0, stream>>>(
      ffh, tgt3, nullptr, ff1w, ff1b, FFNn, Dn, Dn, 1.f, 1);

  // 10. FFN2 split-K x4 -> partials
  gemm32_kernel<<<dim3(Dn / 32, MQ / 32, 4), dim3(256), 0, stream>>>(
      part, ffh, nullptr, ff2w, nullptr, Dn, 256, FFNn, 1.f, 0);

  // 11. out = LN3(tgt3 + sum(part) + ff2b)
  reduce_ln_kernel<<<dim3(MQ), dim3(256), 0, stream>>>(
      out, part, ff2b, tgt3, ln3g, ln3b, 4);
}